// Round 8
// baseline (227.616 us; speedup 1.0000x reference)
//
#include <hip/hip_runtime.h>
#include <math.h>

// ---------------- constants ----------------
#define PHI_F      ((float)1.6180339887498948482045868343656381177)
#define B_  8
#define S_  128
#define D_  256
#define H_  8
#define DH_ 32
#define NN_ 256
#define V_  32000
#define M_  (B_ * S_)   // 1024 rows, m = t*8 + b

typedef __attribute__((ext_vector_type(4))) float f32x4;
typedef __attribute__((ext_vector_type(8))) short bf16x8;

__device__ __forceinline__ unsigned short f2bf_rne(float x) {
    unsigned u = __float_as_uint(x);
    unsigned r = (u + 0x7FFFu + ((u >> 16) & 1u)) >> 16;
    return (unsigned short)r;
}

__device__ __forceinline__ void split_hl(float x, unsigned short& h, unsigned short& l) {
    h = f2bf_rne(x);
    float hf = __uint_as_float(((unsigned)h) << 16);
    l = f2bf_rne(__fsub_rn(x, hf));
}

// ---------------- K0: merged independent preps ------------------------------
// [0,256) res prep; [256,1280) h prep; [1280,9280) Wout split;
// [9280,9408) Wc split; [9408,9600) BB build+split.
__global__ __launch_bounds__(256) void k_prep_all(
    const int* __restrict__ ids, const float* __restrict__ emb,
    const float* __restrict__ Wres, const float* __restrict__ Bres,
    const float* __restrict__ Wout, const float* __restrict__ Wc,
    const float* __restrict__ Wr, const float* __restrict__ Wi,
    const float* __restrict__ Wor, const float* __restrict__ Woi,
    float* __restrict__ winvT, float* __restrict__ bresT,
    float* __restrict__ hwinv, float* __restrict__ hcbuf,
    unsigned short* __restrict__ Wo_h, unsigned short* __restrict__ Wo_l,
    unsigned short* __restrict__ Wc_h, unsigned short* __restrict__ Wc_l,
    unsigned short* __restrict__ BB_h, unsigned short* __restrict__ BB_l)
{
    const int blk = blockIdx.x;
    const int tid = threadIdx.x;
    if (blk < 256) {
        int i = blk * 256 + tid;              // i = n*256+d
        int n = i >> 8, d = i & 255;
        winvT[d * NN_ + n] = 1.0f / (1.0f + fabsf(Wres[i]));
        bresT[d * NN_ + n] = Bres[i];
    } else if (blk < 1280) {
        int m = blk - 256, d = tid;
        int t = m >> 3, b = m & 7;
        int id = ids[b * S_ + t];
        float w  = emb[(size_t)id * (2 * D_) + d];
        float bt = emb[(size_t)id * (2 * D_) + D_ + d];
        hwinv[(size_t)m * D_ + d] = 1.0f / (1.0f + fabsf(w));
        hcbuf[(size_t)m * D_ + d] = 2.0f * (bt + (float)t * PHI_F);
    } else if (blk < 9280) {
        int i = ((blk - 1280) * 256 + tid) * 4;    // < V_*256
        float4 v = *(const float4*)&Wout[i];
        float xs[4] = {v.x, v.y, v.z, v.w};
        ushort hs[4], ls[4];
        #pragma unroll
        for (int j = 0; j < 4; ++j) split_hl(xs[j], hs[j], ls[j]);
        *(ushort4*)&Wo_h[i] = make_ushort4(hs[0], hs[1], hs[2], hs[3]);
        *(ushort4*)&Wo_l[i] = make_ushort4(ls[0], ls[1], ls[2], ls[3]);
    } else if (blk < 9408) {
        int i = ((blk - 9280) * 256 + tid) * 4;    // < 256*512
        float4 v = *(const float4*)&Wc[i];
        float xs[4] = {v.x, v.y, v.z, v.w};
        ushort hs[4], ls[4];
        #pragma unroll
        for (int j = 0; j < 4; ++j) split_hl(xs[j], hs[j], ls[j]);
        *(ushort4*)&Wc_h[i] = make_ushort4(hs[0], hs[1], hs[2], hs[3]);
        *(ushort4*)&Wc_l[i] = make_ushort4(ls[0], ls[1], ls[2], ls[3]);
    } else {
        int i = ((blk - 9408) * 256 + tid) * 4;    // < 256*768, BB[n][k]
        int n = i / 768, k = i % 768;
        float4 v;
        if (k < 256) {
            float4 a = *(const float4*)&Wr[n * 256 + k];
            float4 b = *(const float4*)&Wi[n * 256 + k];
            v.x = a.x + b.x; v.y = a.y + b.y; v.z = a.z + b.z; v.w = a.w + b.w;
        } else if (k < 512) {
            v = *(const float4*)&Wor[n * 256 + (k - 256)];
        } else {
            v = *(const float4*)&Woi[n * 256 + (k - 512)];
        }
        float xs[4] = {v.x, v.y, v.z, v.w};
        ushort hs[4], ls[4];
        #pragma unroll
        for (int j = 0; j < 4; ++j) split_hl(xs[j], hs[j], ls[j]);
        *(ushort4*)&BB_h[i] = make_ushort4(hs[0], hs[1], hs[2], hs[3]);
        *(ushort4*)&BB_l[i] = make_ushort4(ls[0], ls[1], ls[2], ls[3]);
    }
}

// ---------------- K1: sequential h-recurrence + fused Q/K generation --------
// thread (b,d): u_t = x_{t-1}*winv + c; h_r=cos u, h_i=sin u, x=cos+sin.
// Q/K: mapping (h,j) = (d>>5, d&31) so wq/bq index h*DH+j == d.
__global__ __launch_bounds__(64) void k_hscan2(
    const float* __restrict__ winv, const float* __restrict__ cbuf,
    const float* __restrict__ wq, const float* __restrict__ bq,
    const float* __restrict__ wk, const float* __restrict__ bk,
    unsigned short* __restrict__ hri_h, unsigned short* __restrict__ hri_l,
    float* __restrict__ xbuf, float* __restrict__ qbuf, float* __restrict__ kbuf)
{
    int e = blockIdx.x * 64 + threadIdx.x;   // 0..2047
    int b = e >> 8, d = e & 255;
    float invq = 1.0f / (1.0f + fabsf(wq[d]));
    float bqv  = bq[d];
    float invk = 1.0f / (1.0f + fabsf(wk[d]));
    float bkv  = bk[d];
    int qoff = (d >> 5) * 64 + (d & 31);
    float x = 0.f;
    for (int t = 0; t < S_; ++t) {
        int m = (t << 3) | b;
        float wi = winv[(size_t)m * D_ + d];
        float c  = cbuf[(size_t)m * D_ + d];
        float u  = fmaf(x, wi, c);
        float s, co;
        __sincosf(u, &s, &co);
        x = co + s;
        ushort hh, hl, sh, sl;
        split_hl(co, hh, hl);
        split_hl(s,  sh, sl);
        hri_h[(size_t)m * 512 + d]       = hh;
        hri_l[(size_t)m * 512 + d]       = hl;
        hri_h[(size_t)m * 512 + 256 + d] = sh;
        hri_l[(size_t)m * 512 + 256 + d] = sl;
        xbuf[(size_t)m * D_ + d]         = x;
        // Q (with t*PHI) and K (without) phase vectors — off the carried path
        float tp = (float)t * PHI_F;
        float sq, cq, sk, ck;
        __sincosf(fmaf(x, invq, bqv) + tp, &sq, &cq);
        __sincosf(fmaf(x, invk, bkv), &sk, &ck);
        qbuf[(size_t)m * 512 + qoff]      = cq;
        qbuf[(size_t)m * 512 + qoff + 32] = sq;
        kbuf[(size_t)m * 512 + qoff]      = ck;
        kbuf[(size_t)m * 512 + qoff + 32] = sk;
    }
}

// ---------------- K3: causal phase attention -> G[:,0:256] (hi/lo) ----------
// wave-parallel softmax: 32 lanes per head, shfl_xor tree reduce
__global__ __launch_bounds__(256) void k_attn(
    const float* __restrict__ qbuf, const float* __restrict__ kbuf,
    const float* __restrict__ xbuf,
    unsigned short* __restrict__ G_h, unsigned short* __restrict__ G_l)
{
    int m = blockIdx.x;
    int t = m >> 3, b = m & 7;
    int tid = threadIdx.x;
    if (t == 0) {
        G_h[(size_t)m * 768 + tid] = 0;
        G_l[(size_t)m * 768 + tid] = 0;
        return;
    }
    __shared__ float qs[512];
    __shared__ float sc[8][128];
    __shared__ float invdn[8];
    __shared__ float wsum[128];
    qs[tid]       = qbuf[(size_t)m * 512 + tid];
    qs[tid + 256] = qbuf[(size_t)m * 512 + 256 + tid];
    __syncthreads();
    int h = tid & 7;
    for (int s = tid >> 3; s < t; s += 32) {
        const float* kk = kbuf + (size_t)((s << 3) | b) * 512 + h * 64;
        const float* qq = qs + h * 64;
        float dot = 0.f;
        #pragma unroll
        for (int e = 0; e < 64; ++e) dot += qq[e] * kk[e];
        sc[h][s] = dot * 0.125f;
    }
    __syncthreads();
    // parallel softmax: head hh = tid>>5, lane j = tid&31
    int hh = tid >> 5, j = tid & 31;
    float mx = -1e30f;
    for (int s = j; s < t; s += 32) mx = fmaxf(mx, sc[hh][s]);
    #pragma unroll
    for (int o = 16; o; o >>= 1) mx = fmaxf(mx, __shfl_xor(mx, o, 32));
    float dn = 0.f;
    for (int s = j; s < t; s += 32) {
        float e2 = expf(sc[hh][s] - mx);
        sc[hh][s] = e2;
        dn += e2;
    }
    #pragma unroll
    for (int o = 16; o; o >>= 1) dn += __shfl_xor(dn, o, 32);
    if (j == 0) invdn[hh] = 1.0f / dn;
    __syncthreads();
    if (tid < t) {
        float wv = 0.f;
        #pragma unroll
        for (int h2 = 0; h2 < 8; ++h2) wv += sc[h2][tid] * invdn[h2];
        wsum[tid] = wv;
    }
    __syncthreads();
    float a0 = 0.f, a1 = 0.f, a2 = 0.f, a3 = 0.f;
    int s = 0;
    for (; s + 4 <= t; s += 4) {
        a0 += wsum[s + 0] * xbuf[(size_t)(((s + 0) << 3) | b) * D_ + tid];
        a1 += wsum[s + 1] * xbuf[(size_t)(((s + 1) << 3) | b) * D_ + tid];
        a2 += wsum[s + 2] * xbuf[(size_t)(((s + 2) << 3) | b) * D_ + tid];
        a3 += wsum[s + 3] * xbuf[(size_t)(((s + 3) << 3) | b) * D_ + tid];
    }
    for (; s < t; ++s) a0 += wsum[s] * xbuf[(size_t)((s << 3) | b) * D_ + tid];
    float v = (a0 + a1) + (a2 + a3);
    ushort hu, lu;
    split_hl(v, hu, lu);
    G_h[(size_t)m * 768 + tid] = hu;
    G_l[(size_t)m * 768 + tid] = lu;
}

// ---------------- K4: resonant layer -> G[:,256:768] (hi/lo) ----------------
__global__ __launch_bounds__(256) void k_res2(
    const float* __restrict__ xc,
    const float* __restrict__ winvT, const float* __restrict__ bresT,
    unsigned short* __restrict__ G_h, unsigned short* __restrict__ G_l)
{
    __shared__ float s_xc0[D_], s_xc1[D_];
    const int m0 = blockIdx.x * 2;
    const int tid = threadIdx.x;
    s_xc0[tid] = xc[(size_t)m0 * D_ + tid];
    s_xc1[tid] = xc[(size_t)(m0 + 1) * D_ + tid];
    __syncthreads();
    const int n = tid;
    const float tp = __fmul_rn((float)(m0 >> 3), PHI_F);
    float cs0 = 0.f, ss0 = 0.f, cs1 = 0.f, ss1 = 0.f;
    #pragma unroll 4
    for (int d = 0; d < D_; ++d) {
        float wi = winvT[d * NN_ + n];
        float bt = bresT[d * NN_ + n] + tp;
        float th0 = fmaf(s_xc0[d], wi, bt);
        float th1 = fmaf(s_xc1[d], wi, bt);
        cs0 += __cosf(th0); ss0 += __sinf(th0);
        cs1 += __cosf(th1); ss1 += __sinf(th1);
    }
    ushort h0, l0, h1, l1, h2, l2, h3, l3;
    split_hl(cs0, h0, l0); split_hl(ss0, h1, l1);
    split_hl(cs1, h2, l2); split_hl(ss1, h3, l3);
    G_h[(size_t)m0 * 768 + 256 + n] = h0; G_l[(size_t)m0 * 768 + 256 + n] = l0;
    G_h[(size_t)m0 * 768 + 512 + n] = h1; G_l[(size_t)m0 * 768 + 512 + n] = l1;
    G_h[(size_t)(m0 + 1) * 768 + 256 + n] = h2; G_l[(size_t)(m0 + 1) * 768 + 256 + n] = l2;
    G_h[(size_t)(m0 + 1) * 768 + 512 + n] = h3; G_l[(size_t)(m0 + 1) * 768 + 512 + n] = l3;
}

// ---------------- gemm_small: MFMA bf16 3-term, 128x128 tile, K-dbuf --------
// Only ~16 blocks in flight -> no inter-block overlap; double-buffer staging
// (T3-min pattern: STAGE next before compute current, one barrier per tile).
__global__ __launch_bounds__(256) void gemm_small(
    const unsigned short* __restrict__ Ah, const unsigned short* __restrict__ Al, int lda,
    const unsigned short* __restrict__ Bh, const unsigned short* __restrict__ Bl, int ldb,
    int K, const float* __restrict__ bias,
    float* __restrict__ outF, int ldc, int mode,
    unsigned short* __restrict__ Oh, unsigned short* __restrict__ Ol)
{
    __shared__ unsigned short sAh[2][128 * 64], sAl[2][128 * 64];
    __shared__ unsigned short sBh[2][128 * 64], sBl[2][128 * 64];
    const int n0 = blockIdx.x * 128;
    const int m0 = blockIdx.y * 128;
    const int tid  = threadIdx.x;
    const int lane = tid & 63;
    const int wv   = tid >> 6;
    const int wr   = wv >> 1, wc = wv & 1;
    f32x4 acc[4][4] = {};

    auto STAGE = [&](int buf, int k0) {
        #pragma unroll
        for (int q = 0; q < 4; ++q) {
            int idx  = q * 256 + tid;
            int row  = idx >> 3;
            int slot = (idx & 7) ^ (row & 7);
            int ldsbase = (q * 256 + wv * 64) * 8;
            size_t ga = (size_t)(m0 + row) * lda + k0 + slot * 8;
            size_t gb = (size_t)(n0 + row) * ldb + k0 + slot * 8;
            __builtin_amdgcn_global_load_lds(
                (const __attribute__((address_space(1))) void*)(Ah + ga),
                (__attribute__((address_space(3))) void*)(&sAh[buf][ldsbase]), 16, 0, 0);
            __builtin_amdgcn_global_load_lds(
                (const __attribute__((address_space(1))) void*)(Al + ga),
                (__attribute__((address_space(3))) void*)(&sAl[buf][ldsbase]), 16, 0, 0);
            __builtin_amdgcn_global_load_lds(
                (const __attribute__((address_space(1))) void*)(Bh + gb),
                (__attribute__((address_space(3))) void*)(&sBh[buf][ldsbase]), 16, 0, 0);
            __builtin_amdgcn_global_load_lds(
                (const __attribute__((address_space(1))) void*)(Bl + gb),
                (__attribute__((address_space(3))) void*)(&sBl[buf][ldsbase]), 16, 0, 0);
        }
    };

    const int nit = K >> 6;
    STAGE(0, 0);
    __syncthreads();
    for (int it = 0; it < nit; ++it) {
        int cur = it & 1;
        if (it + 1 < nit) STAGE(cur ^ 1, (it + 1) << 6);
        #pragma unroll
        for (int ks = 0; ks < 2; ++ks) {
            const int kg = ks * 4 + (lane >> 4);
            bf16x8 afh[4], afl[4], bfh[4], bfl[4];
            #pragma unroll
            for (int mi = 0; mi < 4; ++mi) {
                int row  = wr * 64 + mi * 16 + (lane & 15);
                int slot = kg ^ (row & 7);
                afh[mi] = *(const bf16x8*)&sAh[cur][row * 64 + slot * 8];
                afl[mi] = *(const bf16x8*)&sAl[cur][row * 64 + slot * 8];
            }
            #pragma unroll
            for (int nj = 0; nj < 4; ++nj) {
                int row  = wc * 64 + nj * 16 + (lane & 15);
                int slot = kg ^ (row & 7);
                bfh[nj] = *(const bf16x8*)&sBh[cur][row * 64 + slot * 8];
                bfl[nj] = *(const bf16x8*)&sBl[cur][row * 64 + slot * 8];
            }
            #pragma unroll
            for (int mi = 0; mi < 4; ++mi)
                #pragma unroll
                for (int nj = 0; nj < 4; ++nj) {
                    acc[mi][nj] = __builtin_amdgcn_mfma_f32_16x16x32_bf16(afh[mi], bfh[nj], acc[mi][nj], 0, 0, 0);
                    acc[mi][nj] = __builtin_amdgcn_mfma_f32_16x16x32_bf16(afh[mi], bfl[nj], acc[mi][nj], 0, 0, 0);
                    acc[mi][nj] = __builtin_amdgcn_mfma_f32_16x16x32_bf16(afl[mi], bfh[nj], acc[mi][nj], 0, 0, 0);
                }
        }
        __syncthreads();
    }

    #pragma unroll
    for (int mi = 0; mi < 4; ++mi)
        #pragma unroll
        for (int nj = 0; nj < 4; ++nj)
            #pragma unroll
            for (int r = 0; r < 4; ++r) {
                int m = m0 + wr * 64 + mi * 16 + (lane >> 4) * 4 + r;
                int n = n0 + wc * 64 + nj * 16 + (lane & 15);
                float v = acc[mi][nj][r];
                if (mode == 0) {
                    outF[(size_t)m * ldc + n] = v + bias[n];
                } else {
                    ushort hu, lu;
                    split_hl(v, hu, lu);
                    Oh[(size_t)m * ldc + n] = hu;
                    Ol[(size_t)m * ldc + n] = lu;
                }
            }
}

// ---------------- K7 v3: logits GEMM, XCD-panel-grouped ordering ------------
__global__ __launch_bounds__(256) void gemm_logits3(
    const unsigned short* __restrict__ Ah, const unsigned short* __restrict__ Al,
    const unsigned short* __restrict__ Bh, const unsigned short* __restrict__ Bl,
    float* __restrict__ out)
{
    const int blk = blockIdx.x;
    const int r = blk & 7, mt = (blk >> 3) & 7, j = blk >> 6;
    const int p = j * 8 + r;
    if (p >= V_ / 128) return;
    const int n0 = p * 128;
    const int m0 = mt * 128;

    __shared__ unsigned short sAh[128 * 64], sAl[128 * 64];
    __shared__ unsigned short sBh[128 * 64], sBl[128 * 64];
    const int tid  = threadIdx.x;
    const int lane = tid & 63;
    const int wv   = tid >> 6;
    const int wr   = wv >> 1, wc = wv & 1;
    f32x4 acc[4][4] = {};

    for (int k0 = 0; k0 < 256; k0 += 64) {
        #pragma unroll
        for (int q = 0; q < 4; ++q) {
            int idx  = q * 256 + tid;
            int row  = idx >> 3;
            int slot = (idx & 7) ^ (row & 7);
            int ldsbase = (q * 256 + wv * 64) * 8;
            size_t ga = (size_t)(m0 + row) * 256 + k0 + slot * 8;
            size_t gb = (size_t)(n0 + row) * 256 + k0 + slot * 8;
            __builtin_amdgcn_global_load_lds(
                (const __attribute__((address_space(1))) void*)(Ah + ga),
                (__attribute__((address_space(3))) void*)(sAh + ldsbase), 16, 0, 0);
            __builtin_amdgcn_global_load_lds(
                (const __attribute__((address_space(1))) void*)(Al + ga),
                (__attribute__((address_space(3))) void*)(sAl + ldsbase), 16, 0, 0);
            __builtin_amdgcn_global_load_lds(
                (const __attribute__((address_space(1))) void*)(Bh + gb),
                (__attribute__((address_space(3))) void*)(sBh + ldsbase), 16, 0, 0);
            __builtin_amdgcn_global_load_lds(
                (const __attribute__((address_space(1))) void*)(Bl + gb),
                (__attribute__((address_space(3))) void*)(sBl + ldsbase), 16, 0, 0);
        }
        __syncthreads();

        #pragma unroll
        for (int ks = 0; ks < 2; ++ks) {
            const int kg = ks * 4 + (lane >> 4);
            bf16x8 afh[4], afl[4], bfh[4], bfl[4];
            #pragma unroll
            for (int mi = 0; mi < 4; ++mi) {
                int row  = wr * 64 + mi * 16 + (lane & 15);
                int slot = kg ^ (row & 7);
                afh[mi] = *(const bf16x8*)&sAh[row * 64 + slot * 8];
                afl[mi] = *(const bf16x8*)&sAl[row * 64 + slot * 8];
            }
            #pragma unroll
            for (int nj = 0; nj < 4; ++nj) {
                int row  = wc * 64 + nj * 16 + (lane & 15);
                int slot = kg ^ (row & 7);
                bfh[nj] = *(const bf16x8*)&sBh[row * 64 + slot * 8];
                bfl[nj] = *(const bf16x8*)&sBl[row * 64 + slot * 8];
            }
            #pragma unroll
            for (int mi = 0; mi < 4; ++mi)
                #pragma unroll
                for (int nj = 0; nj < 4; ++nj) {
                    acc[mi][nj] = __builtin_amdgcn_mfma_f32_16x16x32_bf16(afh[mi], bfh[nj], acc[mi][nj], 0, 0, 0);
                    acc[mi][nj] = __builtin_amdgcn_mfma_f32_16x16x32_bf16(afh[mi], bfl[nj], acc[mi][nj], 0, 0, 0);
                    acc[mi][nj] = __builtin_amdgcn_mfma_f32_16x16x32_bf16(afl[mi], bfh[nj], acc[mi][nj], 0, 0, 0);
                }
        }
        __syncthreads();
    }

    #pragma unroll
    for (int mi = 0; mi < 4; ++mi)
        #pragma unroll
        for (int nj = 0; nj < 4; ++nj)
            #pragma unroll
            for (int rr = 0; rr < 4; ++rr) {
                int m = m0 + wr * 64 + mi * 16 + (lane >> 4) * 4 + rr;
                int n = n0 + wc * 64 + nj * 16 + (lane & 15);
                int orow = (m & 7) * S_ + (m >> 3);
                out[(size_t)orow * V_ + n] = acc[mi][nj][rr];
            }
}

// ---------------- launcher ----------------
extern "C" void kernel_launch(void* const* d_in, const int* in_sizes, int n_in,
                              void* d_out, int out_size, void* d_ws, size_t ws_size,
                              hipStream_t stream)
{
    const int*   ids  = (const int*)d_in[0];
    const float* emb  = (const float*)d_in[1];
    const float* wq   = (const float*)d_in[2];
    const float* bq   = (const float*)d_in[3];
    const float* wk   = (const float*)d_in[4];
    const float* bk   = (const float*)d_in[5];
    const float* Wr   = (const float*)d_in[6];
    const float* Wi   = (const float*)d_in[7];
    const float* Wc   = (const float*)d_in[8];
    const float* bc   = (const float*)d_in[9];
    const float* Wres = (const float*)d_in[10];
    const float* Bres = (const float*)d_in[11];
    const float* Wor  = (const float*)d_in[12];
    const float* Woi  = (const float*)d_in[13];
    const float* Wout = (const float*)d_in[14];
    float* out = (float*)d_out;
    float* ws  = (float*)d_ws;

    // f32 region
    float* xbuf  = ws;                         // 1024*256
    float* qbuf  = xbuf + (size_t)M_ * 256;    // 1024*512
    float* kbuf  = qbuf + (size_t)M_ * 512;    // 1024*512
    float* xc    = kbuf + (size_t)M_ * 512;    // 1024*256
    float* winvT = xc   + (size_t)M_ * 256;    // 65536
    float* bresT = winvT + (size_t)NN_ * D_;   // 65536
    float* hwinv = bresT + (size_t)NN_ * D_;   // 1024*256
    float* hcbuf = hwinv + (size_t)M_ * D_;    // 1024*256
    // ushort region
    unsigned short* us = (unsigned short*)(hcbuf + (size_t)M_ * D_);
    unsigned short* hri_h = us;                       us += (size_t)M_ * 512;
    unsigned short* hri_l = us;                       us += (size_t)M_ * 512;
    unsigned short* G_h   = us;                       us += (size_t)M_ * 768;
    unsigned short* G_l   = us;                       us += (size_t)M_ * 768;
    unsigned short* BB_h  = us;                       us += (size_t)256 * 768;
    unsigned short* BB_l  = us;                       us += (size_t)256 * 768;
    unsigned short* Wc_h  = us;                       us += (size_t)256 * 512;
    unsigned short* Wc_l  = us;                       us += (size_t)256 * 512;
    unsigned short* fus_h = us;                       us += (size_t)M_ * 256;
    unsigned short* fus_l = us;                       us += (size_t)M_ * 256;
    unsigned short* Wo_h  = us;                       us += (size_t)V_ * 256;
    unsigned short* Wo_l  = us;

    k_prep_all<<<dim3(9600), dim3(256), 0, stream>>>(
        ids, emb, Wres, Bres, Wout, Wc, Wr, Wi, Wor, Woi,
        winvT, bresT, hwinv, hcbuf,
        Wo_h, Wo_l, Wc_h, Wc_l, BB_h, BB_l);
    k_hscan2<<<dim3(2048 / 64), dim3(64), 0, stream>>>(
        hwinv, hcbuf, wq, bq, wk, bk, hri_h, hri_l, xbuf, qbuf, kbuf);
    k_attn<<<dim3(M_), dim3(256), 0, stream>>>(qbuf, kbuf, xbuf, G_h, G_l);
    // xc = [h_r|h_i] @ Wc^T + bc   (M=1024, N=256, K=512) via MFMA, dbuf
    gemm_small<<<dim3(2, 8), dim3(256), 0, stream>>>(
        hri_h, hri_l, 512, Wc_h, Wc_l, 512, 512, bc, xc, 256, 0, nullptr, nullptr);
    k_res2<<<dim3(M_ / 2), dim3(256), 0, stream>>>(xc, winvT, bresT, G_h, G_l);
    // fused = G @ BB^T  (M=1024, N=256, K=768) via MFMA, epilogue hi/lo split
    gemm_small<<<dim3(2, 8), dim3(256), 0, stream>>>(
        G_h, G_l, 768, BB_h, BB_l, 768, 768, nullptr, nullptr, 256, 2, fus_h, fus_l);
    // logits = fused @ Wout^T via bf16x3 MFMA, XCD-panel-grouped grid
    gemm_logits3<<<dim3(2048), dim3(256), 0, stream>>>(fus_h, fus_l, Wo_h, Wo_l, out);
}

// Round 9
// 201.426 us; speedup vs baseline: 1.1300x; 1.1300x over previous
//
#include <hip/hip_runtime.h>
#include <math.h>

// ---------------- constants ----------------
#define PHI_F      ((float)1.6180339887498948482045868343656381177)
#define B_  8
#define S_  128
#define D_  256
#define H_  8
#define DH_ 32
#define NN_ 256
#define V_  32000
#define M_  (B_ * S_)   // 1024 rows, m = t*8 + b

typedef __attribute__((ext_vector_type(4))) float f32x4;
typedef __attribute__((ext_vector_type(8))) short bf16x8;

__device__ __forceinline__ unsigned short f2bf_rne(float x) {
    unsigned u = __float_as_uint(x);
    unsigned r = (u + 0x7FFFu + ((u >> 16) & 1u)) >> 16;
    return (unsigned short)r;
}

__device__ __forceinline__ void split_hl(float x, unsigned short& h, unsigned short& l) {
    h = f2bf_rne(x);
    float hf = __uint_as_float(((unsigned)h) << 16);
    l = f2bf_rne(__fsub_rn(x, hf));
}

// ---------------- K0: merged independent preps ------------------------------
// [0,256) res prep; [256,1280) h prep; [1280,9280) Wout split;
// [9280,9408) Wc split; [9408,9600) BB build+split.
__global__ __launch_bounds__(256) void k_prep_all(
    const int* __restrict__ ids, const float* __restrict__ emb,
    const float* __restrict__ Wres, const float* __restrict__ Bres,
    const float* __restrict__ Wout, const float* __restrict__ Wc,
    const float* __restrict__ Wr, const float* __restrict__ Wi,
    const float* __restrict__ Wor, const float* __restrict__ Woi,
    float* __restrict__ winvT, float* __restrict__ bresT,
    float* __restrict__ hwinv, float* __restrict__ hcbuf,
    unsigned short* __restrict__ Wo_h, unsigned short* __restrict__ Wo_l,
    unsigned short* __restrict__ Wc_h, unsigned short* __restrict__ Wc_l,
    unsigned short* __restrict__ BB_h, unsigned short* __restrict__ BB_l)
{
    const int blk = blockIdx.x;
    const int tid = threadIdx.x;
    if (blk < 256) {
        int i = blk * 256 + tid;              // i = n*256+d
        int n = i >> 8, d = i & 255;
        winvT[d * NN_ + n] = 1.0f / (1.0f + fabsf(Wres[i]));
        bresT[d * NN_ + n] = Bres[i];
    } else if (blk < 1280) {
        int m = blk - 256, d = tid;
        int t = m >> 3, b = m & 7;
        int id = ids[b * S_ + t];
        float w  = emb[(size_t)id * (2 * D_) + d];
        float bt = emb[(size_t)id * (2 * D_) + D_ + d];
        hwinv[(size_t)m * D_ + d] = 1.0f / (1.0f + fabsf(w));
        hcbuf[(size_t)m * D_ + d] = 2.0f * (bt + (float)t * PHI_F);
    } else if (blk < 9280) {
        int i = ((blk - 1280) * 256 + tid) * 4;    // < V_*256
        float4 v = *(const float4*)&Wout[i];
        float xs[4] = {v.x, v.y, v.z, v.w};
        ushort hs[4], ls[4];
        #pragma unroll
        for (int j = 0; j < 4; ++j) split_hl(xs[j], hs[j], ls[j]);
        *(ushort4*)&Wo_h[i] = make_ushort4(hs[0], hs[1], hs[2], hs[3]);
        *(ushort4*)&Wo_l[i] = make_ushort4(ls[0], ls[1], ls[2], ls[3]);
    } else if (blk < 9408) {
        int i = ((blk - 9280) * 256 + tid) * 4;    // < 256*512
        float4 v = *(const float4*)&Wc[i];
        float xs[4] = {v.x, v.y, v.z, v.w};
        ushort hs[4], ls[4];
        #pragma unroll
        for (int j = 0; j < 4; ++j) split_hl(xs[j], hs[j], ls[j]);
        *(ushort4*)&Wc_h[i] = make_ushort4(hs[0], hs[1], hs[2], hs[3]);
        *(ushort4*)&Wc_l[i] = make_ushort4(ls[0], ls[1], ls[2], ls[3]);
    } else {
        int i = ((blk - 9408) * 256 + tid) * 4;    // < 256*768, BB[n][k]
        int n = i / 768, k = i % 768;
        float4 v;
        if (k < 256) {
            float4 a = *(const float4*)&Wr[n * 256 + k];
            float4 b = *(const float4*)&Wi[n * 256 + k];
            v.x = a.x + b.x; v.y = a.y + b.y; v.z = a.z + b.z; v.w = a.w + b.w;
        } else if (k < 512) {
            v = *(const float4*)&Wor[n * 256 + (k - 256)];
        } else {
            v = *(const float4*)&Woi[n * 256 + (k - 512)];
        }
        float xs[4] = {v.x, v.y, v.z, v.w};
        ushort hs[4], ls[4];
        #pragma unroll
        for (int j = 0; j < 4; ++j) split_hl(xs[j], hs[j], ls[j]);
        *(ushort4*)&BB_h[i] = make_ushort4(hs[0], hs[1], hs[2], hs[3]);
        *(ushort4*)&BB_l[i] = make_ushort4(ls[0], ls[1], ls[2], ls[3]);
    }
}

// ---------------- K1: sequential h-recurrence (angle form, unfused) ---------
__global__ __launch_bounds__(64) void k_hscan2(
    const float* __restrict__ winv, const float* __restrict__ cbuf,
    unsigned short* __restrict__ hri_h, unsigned short* __restrict__ hri_l,
    float* __restrict__ xbuf)
{
    int e = blockIdx.x * 64 + threadIdx.x;   // 0..2047
    int b = e >> 8, d = e & 255;
    float x = 0.f;
    #pragma unroll 4
    for (int t = 0; t < S_; ++t) {
        int m = (t << 3) | b;
        float wi = winv[(size_t)m * D_ + d];
        float c  = cbuf[(size_t)m * D_ + d];
        float u  = fmaf(x, wi, c);
        float s, co;
        __sincosf(u, &s, &co);
        x = co + s;
        ushort hh, hl, sh, sl;
        split_hl(co, hh, hl);
        split_hl(s,  sh, sl);
        hri_h[(size_t)m * 512 + d]       = hh;
        hri_l[(size_t)m * 512 + d]       = hl;
        hri_h[(size_t)m * 512 + 256 + d] = sh;
        hri_l[(size_t)m * 512 + 256 + d] = sl;
        xbuf[(size_t)m * D_ + d]         = x;
    }
}

// ---------------- K2: build Q/K phase vectors (hw sincos, full parallel) ----
__global__ void k_qk(const float* __restrict__ xbuf,
                     const float* __restrict__ wq, const float* __restrict__ bq,
                     const float* __restrict__ wk, const float* __restrict__ bk,
                     float* __restrict__ qbuf, float* __restrict__ kbuf)
{
    int i = blockIdx.x * 256 + threadIdx.x;       // 0 .. 2*half-1
    const int half = S_ * B_ * H_ * DH_;          // 262144
    bool isq = (i < half);
    int r = isq ? i : i - half;
    int j = r & 31;
    int h = (r >> 5) & 7;
    int b = (r >> 8) & 7;
    int t = r >> 11;
    int m = (t << 3) | b;
    float xv = xbuf[(size_t)m * D_ + h * DH_ + j];
    const float* W  = isq ? wq : wk;
    const float* Bv = isq ? bq : bk;
    float inv = 1.0f / (1.0f + fabsf(W[h * DH_ + j]));
    float th = fmaf(xv, inv, Bv[h * DH_ + j]);
    if (isq) th += (float)t * PHI_F;
    float s, c;
    __sincosf(th, &s, &c);
    float* out = isq ? qbuf : kbuf;
    out[(size_t)m * 512 + h * 64 + j]      = c;
    out[(size_t)m * 512 + h * 64 + 32 + j] = s;
}

// ---------------- K3: causal phase attention -> G[:,0:256] (hi/lo) ----------
// wave-parallel softmax: 32 lanes per head, shfl_xor tree reduce
__global__ __launch_bounds__(256) void k_attn(
    const float* __restrict__ qbuf, const float* __restrict__ kbuf,
    const float* __restrict__ xbuf,
    unsigned short* __restrict__ G_h, unsigned short* __restrict__ G_l)
{
    int m = blockIdx.x;
    int t = m >> 3, b = m & 7;
    int tid = threadIdx.x;
    if (t == 0) {
        G_h[(size_t)m * 768 + tid] = 0;
        G_l[(size_t)m * 768 + tid] = 0;
        return;
    }
    __shared__ float qs[512];
    __shared__ float sc[8][128];
    __shared__ float invdn[8];
    __shared__ float wsum[128];
    qs[tid]       = qbuf[(size_t)m * 512 + tid];
    qs[tid + 256] = qbuf[(size_t)m * 512 + 256 + tid];
    __syncthreads();
    int h = tid & 7;
    for (int s = tid >> 3; s < t; s += 32) {
        const float* kk = kbuf + (size_t)((s << 3) | b) * 512 + h * 64;
        const float* qq = qs + h * 64;
        float dot = 0.f;
        #pragma unroll
        for (int e = 0; e < 64; ++e) dot += qq[e] * kk[e];
        sc[h][s] = dot * 0.125f;
    }
    __syncthreads();
    // parallel softmax: head hh = tid>>5, lane j = tid&31
    int hh = tid >> 5, j = tid & 31;
    float mx = -1e30f;
    for (int s = j; s < t; s += 32) mx = fmaxf(mx, sc[hh][s]);
    #pragma unroll
    for (int o = 16; o; o >>= 1) mx = fmaxf(mx, __shfl_xor(mx, o, 32));
    float dn = 0.f;
    for (int s = j; s < t; s += 32) {
        float e2 = expf(sc[hh][s] - mx);
        sc[hh][s] = e2;
        dn += e2;
    }
    #pragma unroll
    for (int o = 16; o; o >>= 1) dn += __shfl_xor(dn, o, 32);
    if (j == 0) invdn[hh] = 1.0f / dn;
    __syncthreads();
    if (tid < t) {
        float wv = 0.f;
        #pragma unroll
        for (int h2 = 0; h2 < 8; ++h2) wv += sc[h2][tid] * invdn[h2];
        wsum[tid] = wv;
    }
    __syncthreads();
    float a0 = 0.f, a1 = 0.f, a2 = 0.f, a3 = 0.f;
    int s = 0;
    for (; s + 4 <= t; s += 4) {
        a0 += wsum[s + 0] * xbuf[(size_t)(((s + 0) << 3) | b) * D_ + tid];
        a1 += wsum[s + 1] * xbuf[(size_t)(((s + 1) << 3) | b) * D_ + tid];
        a2 += wsum[s + 2] * xbuf[(size_t)(((s + 2) << 3) | b) * D_ + tid];
        a3 += wsum[s + 3] * xbuf[(size_t)(((s + 3) << 3) | b) * D_ + tid];
    }
    for (; s < t; ++s) a0 += wsum[s] * xbuf[(size_t)((s << 3) | b) * D_ + tid];
    float v = (a0 + a1) + (a2 + a3);
    ushort hu, lu;
    split_hl(v, hu, lu);
    G_h[(size_t)m * 768 + tid] = hu;
    G_l[(size_t)m * 768 + tid] = lu;
}

// ---------------- K4: resonant layer -> G[:,256:768] (hi/lo) ----------------
__global__ __launch_bounds__(256) void k_res2(
    const float* __restrict__ xc,
    const float* __restrict__ winvT, const float* __restrict__ bresT,
    unsigned short* __restrict__ G_h, unsigned short* __restrict__ G_l)
{
    __shared__ float s_xc0[D_], s_xc1[D_];
    const int m0 = blockIdx.x * 2;
    const int tid = threadIdx.x;
    s_xc0[tid] = xc[(size_t)m0 * D_ + tid];
    s_xc1[tid] = xc[(size_t)(m0 + 1) * D_ + tid];
    __syncthreads();
    const int n = tid;
    const float tp = __fmul_rn((float)(m0 >> 3), PHI_F);
    float cs0 = 0.f, ss0 = 0.f, cs1 = 0.f, ss1 = 0.f;
    #pragma unroll 4
    for (int d = 0; d < D_; ++d) {
        float wi = winvT[d * NN_ + n];
        float bt = bresT[d * NN_ + n] + tp;
        float th0 = fmaf(s_xc0[d], wi, bt);
        float th1 = fmaf(s_xc1[d], wi, bt);
        cs0 += __cosf(th0); ss0 += __sinf(th0);
        cs1 += __cosf(th1); ss1 += __sinf(th1);
    }
    ushort h0, l0, h1, l1, h2, l2, h3, l3;
    split_hl(cs0, h0, l0); split_hl(ss0, h1, l1);
    split_hl(cs1, h2, l2); split_hl(ss1, h3, l3);
    G_h[(size_t)m0 * 768 + 256 + n] = h0; G_l[(size_t)m0 * 768 + 256 + n] = l0;
    G_h[(size_t)m0 * 768 + 512 + n] = h1; G_l[(size_t)m0 * 768 + 512 + n] = l1;
    G_h[(size_t)(m0 + 1) * 768 + 256 + n] = h2; G_l[(size_t)(m0 + 1) * 768 + 256 + n] = l2;
    G_h[(size_t)(m0 + 1) * 768 + 512 + n] = h3; G_l[(size_t)(m0 + 1) * 768 + 512 + n] = l3;
}

// ---------------- gemm_small: MFMA bf16 3-term, 128x128 tile, generic K -----
// single-buffered (dbuf measured neutral: vmcnt(0) drain at barrier)
__global__ __launch_bounds__(256) void gemm_small(
    const unsigned short* __restrict__ Ah, const unsigned short* __restrict__ Al, int lda,
    const unsigned short* __restrict__ Bh, const unsigned short* __restrict__ Bl, int ldb,
    int K, const float* __restrict__ bias,
    float* __restrict__ outF, int ldc, int mode,
    unsigned short* __restrict__ Oh, unsigned short* __restrict__ Ol)
{
    __shared__ unsigned short sAh[128 * 64], sAl[128 * 64];
    __shared__ unsigned short sBh[128 * 64], sBl[128 * 64];
    const int n0 = blockIdx.x * 128;
    const int m0 = blockIdx.y * 128;
    const int tid  = threadIdx.x;
    const int lane = tid & 63;
    const int wv   = tid >> 6;
    const int wr   = wv >> 1, wc = wv & 1;
    f32x4 acc[4][4] = {};

    for (int k0 = 0; k0 < K; k0 += 64) {
        #pragma unroll
        for (int q = 0; q < 4; ++q) {
            int idx  = q * 256 + tid;
            int row  = idx >> 3;
            int slot = (idx & 7) ^ (row & 7);
            int ldsbase = (q * 256 + wv * 64) * 8;
            size_t ga = (size_t)(m0 + row) * lda + k0 + slot * 8;
            size_t gb = (size_t)(n0 + row) * ldb + k0 + slot * 8;
            __builtin_amdgcn_global_load_lds(
                (const __attribute__((address_space(1))) void*)(Ah + ga),
                (__attribute__((address_space(3))) void*)(sAh + ldsbase), 16, 0, 0);
            __builtin_amdgcn_global_load_lds(
                (const __attribute__((address_space(1))) void*)(Al + ga),
                (__attribute__((address_space(3))) void*)(sAl + ldsbase), 16, 0, 0);
            __builtin_amdgcn_global_load_lds(
                (const __attribute__((address_space(1))) void*)(Bh + gb),
                (__attribute__((address_space(3))) void*)(sBh + ldsbase), 16, 0, 0);
            __builtin_amdgcn_global_load_lds(
                (const __attribute__((address_space(1))) void*)(Bl + gb),
                (__attribute__((address_space(3))) void*)(sBl + ldsbase), 16, 0, 0);
        }
        __syncthreads();

        #pragma unroll
        for (int ks = 0; ks < 2; ++ks) {
            const int kg = ks * 4 + (lane >> 4);
            bf16x8 afh[4], afl[4], bfh[4], bfl[4];
            #pragma unroll
            for (int mi = 0; mi < 4; ++mi) {
                int row  = wr * 64 + mi * 16 + (lane & 15);
                int slot = kg ^ (row & 7);
                afh[mi] = *(const bf16x8*)&sAh[row * 64 + slot * 8];
                afl[mi] = *(const bf16x8*)&sAl[row * 64 + slot * 8];
            }
            #pragma unroll
            for (int nj = 0; nj < 4; ++nj) {
                int row  = wc * 64 + nj * 16 + (lane & 15);
                int slot = kg ^ (row & 7);
                bfh[nj] = *(const bf16x8*)&sBh[row * 64 + slot * 8];
                bfl[nj] = *(const bf16x8*)&sBl[row * 64 + slot * 8];
            }
            #pragma unroll
            for (int mi = 0; mi < 4; ++mi)
                #pragma unroll
                for (int nj = 0; nj < 4; ++nj) {
                    acc[mi][nj] = __builtin_amdgcn_mfma_f32_16x16x32_bf16(afh[mi], bfh[nj], acc[mi][nj], 0, 0, 0);
                    acc[mi][nj] = __builtin_amdgcn_mfma_f32_16x16x32_bf16(afh[mi], bfl[nj], acc[mi][nj], 0, 0, 0);
                    acc[mi][nj] = __builtin_amdgcn_mfma_f32_16x16x32_bf16(afl[mi], bfh[nj], acc[mi][nj], 0, 0, 0);
                }
        }
        __syncthreads();
    }

    #pragma unroll
    for (int mi = 0; mi < 4; ++mi)
        #pragma unroll
        for (int nj = 0; nj < 4; ++nj)
            #pragma unroll
            for (int r = 0; r < 4; ++r) {
                int m = m0 + wr * 64 + mi * 16 + (lane >> 4) * 4 + r;
                int n = n0 + wc * 64 + nj * 16 + (lane & 15);
                float v = acc[mi][nj][r];
                if (mode == 0) {
                    outF[(size_t)m * ldc + n] = v + bias[n];
                } else {
                    ushort hu, lu;
                    split_hl(v, hu, lu);
                    Oh[(size_t)m * ldc + n] = hu;
                    Ol[(size_t)m * ldc + n] = lu;
                }
            }
}

// ---------------- K7 v3: logits GEMM, XCD-panel-grouped ordering ------------
__global__ __launch_bounds__(256) void gemm_logits3(
    const unsigned short* __restrict__ Ah, const unsigned short* __restrict__ Al,
    const unsigned short* __restrict__ Bh, const unsigned short* __restrict__ Bl,
    float* __restrict__ out)
{
    const int blk = blockIdx.x;
    const int r = blk & 7, mt = (blk >> 3) & 7, j = blk >> 6;
    const int p = j * 8 + r;
    if (p >= V_ / 128) return;
    const int n0 = p * 128;
    const int m0 = mt * 128;

    __shared__ unsigned short sAh[128 * 64], sAl[128 * 64];
    __shared__ unsigned short sBh[128 * 64], sBl[128 * 64];
    const int tid  = threadIdx.x;
    const int lane = tid & 63;
    const int wv   = tid >> 6;
    const int wr   = wv >> 1, wc = wv & 1;
    f32x4 acc[4][4] = {};

    for (int k0 = 0; k0 < 256; k0 += 64) {
        #pragma unroll
        for (int q = 0; q < 4; ++q) {
            int idx  = q * 256 + tid;
            int row  = idx >> 3;
            int slot = (idx & 7) ^ (row & 7);
            int ldsbase = (q * 256 + wv * 64) * 8;
            size_t ga = (size_t)(m0 + row) * 256 + k0 + slot * 8;
            size_t gb = (size_t)(n0 + row) * 256 + k0 + slot * 8;
            __builtin_amdgcn_global_load_lds(
                (const __attribute__((address_space(1))) void*)(Ah + ga),
                (__attribute__((address_space(3))) void*)(sAh + ldsbase), 16, 0, 0);
            __builtin_amdgcn_global_load_lds(
                (const __attribute__((address_space(1))) void*)(Al + ga),
                (__attribute__((address_space(3))) void*)(sAl + ldsbase), 16, 0, 0);
            __builtin_amdgcn_global_load_lds(
                (const __attribute__((address_space(1))) void*)(Bh + gb),
                (__attribute__((address_space(3))) void*)(sBh + ldsbase), 16, 0, 0);
            __builtin_amdgcn_global_load_lds(
                (const __attribute__((address_space(1))) void*)(Bl + gb),
                (__attribute__((address_space(3))) void*)(sBl + ldsbase), 16, 0, 0);
        }
        __syncthreads();

        #pragma unroll
        for (int ks = 0; ks < 2; ++ks) {
            const int kg = ks * 4 + (lane >> 4);
            bf16x8 afh[4], afl[4], bfh[4], bfl[4];
            #pragma unroll
            for (int mi = 0; mi < 4; ++mi) {
                int row  = wr * 64 + mi * 16 + (lane & 15);
                int slot = kg ^ (row & 7);
                afh[mi] = *(const bf16x8*)&sAh[row * 64 + slot * 8];
                afl[mi] = *(const bf16x8*)&sAl[row * 64 + slot * 8];
            }
            #pragma unroll
            for (int nj = 0; nj < 4; ++nj) {
                int row  = wc * 64 + nj * 16 + (lane & 15);
                int slot = kg ^ (row & 7);
                bfh[nj] = *(const bf16x8*)&sBh[row * 64 + slot * 8];
                bfl[nj] = *(const bf16x8*)&sBl[row * 64 + slot * 8];
            }
            #pragma unroll
            for (int mi = 0; mi < 4; ++mi)
                #pragma unroll
                for (int nj = 0; nj < 4; ++nj) {
                    acc[mi][nj] = __builtin_amdgcn_mfma_f32_16x16x32_bf16(afh[mi], bfh[nj], acc[mi][nj], 0, 0, 0);
                    acc[mi][nj] = __builtin_amdgcn_mfma_f32_16x16x32_bf16(afh[mi], bfl[nj], acc[mi][nj], 0, 0, 0);
                    acc[mi][nj] = __builtin_amdgcn_mfma_f32_16x16x32_bf16(afl[mi], bfh[nj], acc[mi][nj], 0, 0, 0);
                }
        }
        __syncthreads();
    }

    #pragma unroll
    for (int mi = 0; mi < 4; ++mi)
        #pragma unroll
        for (int nj = 0; nj < 4; ++nj)
            #pragma unroll
            for (int rr = 0; rr < 4; ++rr) {
                int m = m0 + wr * 64 + mi * 16 + (lane >> 4) * 4 + rr;
                int n = n0 + wc * 64 + nj * 16 + (lane & 15);
                int orow = (m & 7) * S_ + (m >> 3);
                out[(size_t)orow * V_ + n] = acc[mi][nj][rr];
            }
}

// ---------------- launcher ----------------
extern "C" void kernel_launch(void* const* d_in, const int* in_sizes, int n_in,
                              void* d_out, int out_size, void* d_ws, size_t ws_size,
                              hipStream_t stream)
{
    const int*   ids  = (const int*)d_in[0];
    const float* emb  = (const float*)d_in[1];
    const float* wq   = (const float*)d_in[2];
    const float* bq   = (const float*)d_in[3];
    const float* wk   = (const float*)d_in[4];
    const float* bk   = (const float*)d_in[5];
    const float* Wr   = (const float*)d_in[6];
    const float* Wi   = (const float*)d_in[7];
    const float* Wc   = (const float*)d_in[8];
    const float* bc   = (const float*)d_in[9];
    const float* Wres = (const float*)d_in[10];
    const float* Bres = (const float*)d_in[11];
    const float* Wor  = (const float*)d_in[12];
    const float* Woi  = (const float*)d_in[13];
    const float* Wout = (const float*)d_in[14];
    float* out = (float*)d_out;
    float* ws  = (float*)d_ws;

    // f32 region
    float* xbuf  = ws;                         // 1024*256
    float* qbuf  = xbuf + (size_t)M_ * 256;    // 1024*512
    float* kbuf  = qbuf + (size_t)M_ * 512;    // 1024*512
    float* xc    = kbuf + (size_t)M_ * 512;    // 1024*256
    float* winvT = xc   + (size_t)M_ * 256;    // 65536
    float* bresT = winvT + (size_t)NN_ * D_;   // 65536
    float* hwinv = bresT + (size_t)NN_ * D_;   // 1024*256
    float* hcbuf = hwinv + (size_t)M_ * D_;    // 1024*256
    // ushort region
    unsigned short* us = (unsigned short*)(hcbuf + (size_t)M_ * D_);
    unsigned short* hri_h = us;                       us += (size_t)M_ * 512;
    unsigned short* hri_l = us;                       us += (size_t)M_ * 512;
    unsigned short* G_h   = us;                       us += (size_t)M_ * 768;
    unsigned short* G_l   = us;                       us += (size_t)M_ * 768;
    unsigned short* BB_h  = us;                       us += (size_t)256 * 768;
    unsigned short* BB_l  = us;                       us += (size_t)256 * 768;
    unsigned short* Wc_h  = us;                       us += (size_t)256 * 512;
    unsigned short* Wc_l  = us;                       us += (size_t)256 * 512;
    unsigned short* fus_h = us;                       us += (size_t)M_ * 256;
    unsigned short* fus_l = us;                       us += (size_t)M_ * 256;
    unsigned short* Wo_h  = us;                       us += (size_t)V_ * 256;
    unsigned short* Wo_l  = us;

    k_prep_all<<<dim3(9600), dim3(256), 0, stream>>>(
        ids, emb, Wres, Bres, Wout, Wc, Wr, Wi, Wor, Woi,
        winvT, bresT, hwinv, hcbuf,
        Wo_h, Wo_l, Wc_h, Wc_l, BB_h, BB_l);
    k_hscan2<<<dim3(2048 / 64), dim3(64), 0, stream>>>(hwinv, hcbuf, hri_h, hri_l, xbuf);
    k_qk<<<dim3(2048), dim3(256), 0, stream>>>(xbuf, wq, bq, wk, bk, qbuf, kbuf);
    k_attn<<<dim3(M_), dim3(256), 0, stream>>>(qbuf, kbuf, xbuf, G_h, G_l);
    // xc = [h_r|h_i] @ Wc^T + bc   (M=1024, N=256, K=512) via MFMA
    gemm_small<<<dim3(2, 8), dim3(256), 0, stream>>>(
        hri_h, hri_l, 512, Wc_h, Wc_l, 512, 512, bc, xc, 256, 0, nullptr, nullptr);
    k_res2<<<dim3(M_ / 2), dim3(256), 0, stream>>>(xc, winvT, bresT, G_h, G_l);
    // fused = G @ BB^T  (M=1024, N=256, K=768) via MFMA, epilogue hi/lo split
    gemm_small<<<dim3(2, 8), dim3(256), 0, stream>>>(
        G_h, G_l, 768, BB_h, BB_l, 768, 768, nullptr, nullptr, 256, 2, fus_h, fus_l);
    // logits = fused @ Wout^T via bf16x3 MFMA, XCD-panel-grouped grid
    gemm_logits3<<<dim3(2048), dim3(256), 0, stream>>>(fus_h, fus_l, Wo_h, Wo_l, out);
}

// Round 10
// 195.552 us; speedup vs baseline: 1.1640x; 1.0300x over previous
//
#include <hip/hip_runtime.h>
#include <math.h>

// ---------------- constants ----------------
#define PHI_F      ((float)1.6180339887498948482045868343656381177)
#define B_  8
#define S_  128
#define D_  256
#define H_  8
#define DH_ 32
#define NN_ 256
#define V_  32000
#define M_  (B_ * S_)   // 1024 rows, m = t*8 + b

typedef __attribute__((ext_vector_type(4))) float f32x4;
typedef __attribute__((ext_vector_type(8))) short bf16x8;

__device__ __forceinline__ unsigned short f2bf_rne(float x) {
    unsigned u = __float_as_uint(x);
    unsigned r = (u + 0x7FFFu + ((u >> 16) & 1u)) >> 16;
    return (unsigned short)r;
}

__device__ __forceinline__ void split_hl(float x, unsigned short& h, unsigned short& l) {
    h = f2bf_rne(x);
    float hf = __uint_as_float(((unsigned)h) << 16);
    l = f2bf_rne(__fsub_rn(x, hf));
}

// ---------------- K0: h prep only (critical path for hscan) -----------------
__global__ __launch_bounds__(256) void k_prep_h(
    const int* __restrict__ ids, const float* __restrict__ emb,
    float* __restrict__ hwinv, float* __restrict__ hcbuf)
{
    int m = blockIdx.x, d = threadIdx.x;
    int t = m >> 3, b = m & 7;
    int id = ids[b * S_ + t];
    float w  = emb[(size_t)id * (2 * D_) + d];
    float bt = emb[(size_t)id * (2 * D_) + D_ + d];
    hwinv[(size_t)m * D_ + d] = 1.0f / (1.0f + fabsf(w));
    hcbuf[(size_t)m * D_ + d] = 2.0f * (bt + (float)t * PHI_F);
}

// ---------------- K1: hscan (8 blocks) + all weight preps riding along ------
// blocks [0,8): sequential h-recurrence (latency-bound, 8 CUs)
// blocks [8,264): res prep; [264,392): Wc split; [392,584): BB build+split;
// blocks [584,8584): Wout split — fills the 248 idle CUs under the scan.
__global__ __launch_bounds__(256) void k_hscan_plus(
    const float* __restrict__ winv, const float* __restrict__ cbuf,
    const float* __restrict__ Wres, const float* __restrict__ Bres,
    const float* __restrict__ Wout, const float* __restrict__ Wc,
    const float* __restrict__ Wr, const float* __restrict__ Wi,
    const float* __restrict__ Wor, const float* __restrict__ Woi,
    unsigned short* __restrict__ hri_h, unsigned short* __restrict__ hri_l,
    float* __restrict__ xbuf,
    float* __restrict__ winvT, float* __restrict__ bresT,
    unsigned short* __restrict__ Wo_h, unsigned short* __restrict__ Wo_l,
    unsigned short* __restrict__ Wc_h, unsigned short* __restrict__ Wc_l,
    unsigned short* __restrict__ BB_h, unsigned short* __restrict__ BB_l)
{
    const int blk = blockIdx.x;
    const int tid = threadIdx.x;
    if (blk < 8) {
        // ---- sequential h-recurrence, e = blk*256+tid, b = blk, d = tid ----
        int b = blk, d = tid;
        float x = 0.f;
        #pragma unroll 4
        for (int t = 0; t < S_; ++t) {
            int m = (t << 3) | b;
            float wi = winv[(size_t)m * D_ + d];
            float c  = cbuf[(size_t)m * D_ + d];
            float u  = fmaf(x, wi, c);
            float s, co;
            __sincosf(u, &s, &co);
            x = co + s;
            ushort hh, hl, sh, sl;
            split_hl(co, hh, hl);
            split_hl(s,  sh, sl);
            hri_h[(size_t)m * 512 + d]       = hh;
            hri_l[(size_t)m * 512 + d]       = hl;
            hri_h[(size_t)m * 512 + 256 + d] = sh;
            hri_l[(size_t)m * 512 + 256 + d] = sl;
            xbuf[(size_t)m * D_ + d]         = x;
        }
    } else if (blk < 264) {
        int i = (blk - 8) * 256 + tid;        // i = n*256+d
        int n = i >> 8, d = i & 255;
        winvT[d * NN_ + n] = 1.0f / (1.0f + fabsf(Wres[i]));
        bresT[d * NN_ + n] = Bres[i];
    } else if (blk < 392) {
        int i = ((blk - 264) * 256 + tid) * 4;    // < 256*512
        float4 v = *(const float4*)&Wc[i];
        float xs[4] = {v.x, v.y, v.z, v.w};
        ushort hs[4], ls[4];
        #pragma unroll
        for (int j = 0; j < 4; ++j) split_hl(xs[j], hs[j], ls[j]);
        *(ushort4*)&Wc_h[i] = make_ushort4(hs[0], hs[1], hs[2], hs[3]);
        *(ushort4*)&Wc_l[i] = make_ushort4(ls[0], ls[1], ls[2], ls[3]);
    } else if (blk < 584) {
        int i = ((blk - 392) * 256 + tid) * 4;    // < 256*768, BB[n][k]
        int n = i / 768, k = i % 768;
        float4 v;
        if (k < 256) {
            float4 a = *(const float4*)&Wr[n * 256 + k];
            float4 b = *(const float4*)&Wi[n * 256 + k];
            v.x = a.x + b.x; v.y = a.y + b.y; v.z = a.z + b.z; v.w = a.w + b.w;
        } else if (k < 512) {
            v = *(const float4*)&Wor[n * 256 + (k - 256)];
        } else {
            v = *(const float4*)&Woi[n * 256 + (k - 512)];
        }
        float xs[4] = {v.x, v.y, v.z, v.w};
        ushort hs[4], ls[4];
        #pragma unroll
        for (int j = 0; j < 4; ++j) split_hl(xs[j], hs[j], ls[j]);
        *(ushort4*)&BB_h[i] = make_ushort4(hs[0], hs[1], hs[2], hs[3]);
        *(ushort4*)&BB_l[i] = make_ushort4(ls[0], ls[1], ls[2], ls[3]);
    } else {
        int i = ((blk - 584) * 256 + tid) * 4;    // < V_*256
        float4 v = *(const float4*)&Wout[i];
        float xs[4] = {v.x, v.y, v.z, v.w};
        ushort hs[4], ls[4];
        #pragma unroll
        for (int j = 0; j < 4; ++j) split_hl(xs[j], hs[j], ls[j]);
        *(ushort4*)&Wo_h[i] = make_ushort4(hs[0], hs[1], hs[2], hs[3]);
        *(ushort4*)&Wo_l[i] = make_ushort4(ls[0], ls[1], ls[2], ls[3]);
    }
}

// ---------------- K2: build Q/K phase vectors (hw sincos, full parallel) ----
__global__ void k_qk(const float* __restrict__ xbuf,
                     const float* __restrict__ wq, const float* __restrict__ bq,
                     const float* __restrict__ wk, const float* __restrict__ bk,
                     float* __restrict__ qbuf, float* __restrict__ kbuf)
{
    int i = blockIdx.x * 256 + threadIdx.x;       // 0 .. 2*half-1
    const int half = S_ * B_ * H_ * DH_;          // 262144
    bool isq = (i < half);
    int r = isq ? i : i - half;
    int j = r & 31;
    int h = (r >> 5) & 7;
    int b = (r >> 8) & 7;
    int t = r >> 11;
    int m = (t << 3) | b;
    float xv = xbuf[(size_t)m * D_ + h * DH_ + j];
    const float* W  = isq ? wq : wk;
    const float* Bv = isq ? bq : bk;
    float inv = 1.0f / (1.0f + fabsf(W[h * DH_ + j]));
    float th = fmaf(xv, inv, Bv[h * DH_ + j]);
    if (isq) th += (float)t * PHI_F;
    float s, c;
    __sincosf(th, &s, &c);
    float* out = isq ? qbuf : kbuf;
    out[(size_t)m * 512 + h * 64 + j]      = c;
    out[(size_t)m * 512 + h * 64 + 32 + j] = s;
}

// ---------------- K3: merged attention (blocks [0,1024)) + resonant ---------
// ([1024,1536)): independent work, disjoint G columns -> run concurrently.
__global__ __launch_bounds__(256) void k_attn_res(
    const float* __restrict__ qbuf, const float* __restrict__ kbuf,
    const float* __restrict__ xbuf, const float* __restrict__ xc,
    const float* __restrict__ winvT, const float* __restrict__ bresT,
    unsigned short* __restrict__ G_h, unsigned short* __restrict__ G_l)
{
    __shared__ float qs[512];
    __shared__ float sc[8][128];
    __shared__ float invdn[8];
    __shared__ float wsum[128];
    const int tid = threadIdx.x;

    if (blockIdx.x < M_) {
        // ---------------- attention -> G[:,0:256] ----------------
        int m = blockIdx.x;
        int t = m >> 3, b = m & 7;
        if (t == 0) {
            G_h[(size_t)m * 768 + tid] = 0;
            G_l[(size_t)m * 768 + tid] = 0;
            return;
        }
        qs[tid]       = qbuf[(size_t)m * 512 + tid];
        qs[tid + 256] = qbuf[(size_t)m * 512 + 256 + tid];
        __syncthreads();
        int h = tid & 7;
        for (int s = tid >> 3; s < t; s += 32) {
            const float* kk = kbuf + (size_t)((s << 3) | b) * 512 + h * 64;
            const float* qq = qs + h * 64;
            float dot = 0.f;
            #pragma unroll
            for (int e = 0; e < 64; ++e) dot += qq[e] * kk[e];
            sc[h][s] = dot * 0.125f;
        }
        __syncthreads();
        int hh = tid >> 5, j = tid & 31;
        float mx = -1e30f;
        for (int s = j; s < t; s += 32) mx = fmaxf(mx, sc[hh][s]);
        #pragma unroll
        for (int o = 16; o; o >>= 1) mx = fmaxf(mx, __shfl_xor(mx, o, 32));
        float dn = 0.f;
        for (int s = j; s < t; s += 32) {
            float e2 = expf(sc[hh][s] - mx);
            sc[hh][s] = e2;
            dn += e2;
        }
        #pragma unroll
        for (int o = 16; o; o >>= 1) dn += __shfl_xor(dn, o, 32);
        if (j == 0) invdn[hh] = 1.0f / dn;
        __syncthreads();
        if (tid < t) {
            float wv = 0.f;
            #pragma unroll
            for (int h2 = 0; h2 < 8; ++h2) wv += sc[h2][tid] * invdn[h2];
            wsum[tid] = wv;
        }
        __syncthreads();
        float a0 = 0.f, a1 = 0.f, a2 = 0.f, a3 = 0.f;
        int s = 0;
        for (; s + 4 <= t; s += 4) {
            a0 += wsum[s + 0] * xbuf[(size_t)(((s + 0) << 3) | b) * D_ + tid];
            a1 += wsum[s + 1] * xbuf[(size_t)(((s + 1) << 3) | b) * D_ + tid];
            a2 += wsum[s + 2] * xbuf[(size_t)(((s + 2) << 3) | b) * D_ + tid];
            a3 += wsum[s + 3] * xbuf[(size_t)(((s + 3) << 3) | b) * D_ + tid];
        }
        for (; s < t; ++s) a0 += wsum[s] * xbuf[(size_t)((s << 3) | b) * D_ + tid];
        float v = (a0 + a1) + (a2 + a3);
        ushort hu, lu;
        split_hl(v, hu, lu);
        G_h[(size_t)m * 768 + tid] = hu;
        G_l[(size_t)m * 768 + tid] = lu;
    } else {
        // ---------------- resonant -> G[:,256:768] ----------------
        const int m0 = (blockIdx.x - M_) * 2;
        float* s_xc0 = qs;          // reuse LDS (256 floats)
        float* s_xc1 = qs + 256;    // (256 floats)
        s_xc0[tid] = xc[(size_t)m0 * D_ + tid];
        s_xc1[tid] = xc[(size_t)(m0 + 1) * D_ + tid];
        __syncthreads();
        const int n = tid;
        const float tp = __fmul_rn((float)(m0 >> 3), PHI_F);
        float cs0 = 0.f, ss0 = 0.f, cs1 = 0.f, ss1 = 0.f;
        #pragma unroll 4
        for (int d = 0; d < D_; ++d) {
            float wi = winvT[d * NN_ + n];
            float bt = bresT[d * NN_ + n] + tp;
            float th0 = fmaf(s_xc0[d], wi, bt);
            float th1 = fmaf(s_xc1[d], wi, bt);
            cs0 += __cosf(th0); ss0 += __sinf(th0);
            cs1 += __cosf(th1); ss1 += __sinf(th1);
        }
        ushort h0, l0, h1, l1, h2, l2, h3, l3;
        split_hl(cs0, h0, l0); split_hl(ss0, h1, l1);
        split_hl(cs1, h2, l2); split_hl(ss1, h3, l3);
        G_h[(size_t)m0 * 768 + 256 + n] = h0; G_l[(size_t)m0 * 768 + 256 + n] = l0;
        G_h[(size_t)m0 * 768 + 512 + n] = h1; G_l[(size_t)m0 * 768 + 512 + n] = l1;
        G_h[(size_t)(m0 + 1) * 768 + 256 + n] = h2; G_l[(size_t)(m0 + 1) * 768 + 256 + n] = l2;
        G_h[(size_t)(m0 + 1) * 768 + 512 + n] = h3; G_l[(size_t)(m0 + 1) * 768 + 512 + n] = l3;
    }
}

// ---------------- gemm_small: MFMA bf16 3-term, 128x128 tile, generic K -----
__global__ __launch_bounds__(256) void gemm_small(
    const unsigned short* __restrict__ Ah, const unsigned short* __restrict__ Al, int lda,
    const unsigned short* __restrict__ Bh, const unsigned short* __restrict__ Bl, int ldb,
    int K, const float* __restrict__ bias,
    float* __restrict__ outF, int ldc, int mode,
    unsigned short* __restrict__ Oh, unsigned short* __restrict__ Ol)
{
    __shared__ unsigned short sAh[128 * 64], sAl[128 * 64];
    __shared__ unsigned short sBh[128 * 64], sBl[128 * 64];
    const int n0 = blockIdx.x * 128;
    const int m0 = blockIdx.y * 128;
    const int tid  = threadIdx.x;
    const int lane = tid & 63;
    const int wv   = tid >> 6;
    const int wr   = wv >> 1, wc = wv & 1;
    f32x4 acc[4][4] = {};

    for (int k0 = 0; k0 < K; k0 += 64) {
        #pragma unroll
        for (int q = 0; q < 4; ++q) {
            int idx  = q * 256 + tid;
            int row  = idx >> 3;
            int slot = (idx & 7) ^ (row & 7);
            int ldsbase = (q * 256 + wv * 64) * 8;
            size_t ga = (size_t)(m0 + row) * lda + k0 + slot * 8;
            size_t gb = (size_t)(n0 + row) * ldb + k0 + slot * 8;
            __builtin_amdgcn_global_load_lds(
                (const __attribute__((address_space(1))) void*)(Ah + ga),
                (__attribute__((address_space(3))) void*)(sAh + ldsbase), 16, 0, 0);
            __builtin_amdgcn_global_load_lds(
                (const __attribute__((address_space(1))) void*)(Al + ga),
                (__attribute__((address_space(3))) void*)(sAl + ldsbase), 16, 0, 0);
            __builtin_amdgcn_global_load_lds(
                (const __attribute__((address_space(1))) void*)(Bh + gb),
                (__attribute__((address_space(3))) void*)(sBh + ldsbase), 16, 0, 0);
            __builtin_amdgcn_global_load_lds(
                (const __attribute__((address_space(1))) void*)(Bl + gb),
                (__attribute__((address_space(3))) void*)(sBl + ldsbase), 16, 0, 0);
        }
        __syncthreads();

        #pragma unroll
        for (int ks = 0; ks < 2; ++ks) {
            const int kg = ks * 4 + (lane >> 4);
            bf16x8 afh[4], afl[4], bfh[4], bfl[4];
            #pragma unroll
            for (int mi = 0; mi < 4; ++mi) {
                int row  = wr * 64 + mi * 16 + (lane & 15);
                int slot = kg ^ (row & 7);
                afh[mi] = *(const bf16x8*)&sAh[row * 64 + slot * 8];
                afl[mi] = *(const bf16x8*)&sAl[row * 64 + slot * 8];
            }
            #pragma unroll
            for (int nj = 0; nj < 4; ++nj) {
                int row  = wc * 64 + nj * 16 + (lane & 15);
                int slot = kg ^ (row & 7);
                bfh[nj] = *(const bf16x8*)&sBh[row * 64 + slot * 8];
                bfl[nj] = *(const bf16x8*)&sBl[row * 64 + slot * 8];
            }
            #pragma unroll
            for (int mi = 0; mi < 4; ++mi)
                #pragma unroll
                for (int nj = 0; nj < 4; ++nj) {
                    acc[mi][nj] = __builtin_amdgcn_mfma_f32_16x16x32_bf16(afh[mi], bfh[nj], acc[mi][nj], 0, 0, 0);
                    acc[mi][nj] = __builtin_amdgcn_mfma_f32_16x16x32_bf16(afh[mi], bfl[nj], acc[mi][nj], 0, 0, 0);
                    acc[mi][nj] = __builtin_amdgcn_mfma_f32_16x16x32_bf16(afl[mi], bfh[nj], acc[mi][nj], 0, 0, 0);
                }
        }
        __syncthreads();
    }

    #pragma unroll
    for (int mi = 0; mi < 4; ++mi)
        #pragma unroll
        for (int nj = 0; nj < 4; ++nj)
            #pragma unroll
            for (int r = 0; r < 4; ++r) {
                int m = m0 + wr * 64 + mi * 16 + (lane >> 4) * 4 + r;
                int n = n0 + wc * 64 + nj * 16 + (lane & 15);
                float v = acc[mi][nj][r];
                if (mode == 0) {
                    outF[(size_t)m * ldc + n] = v + bias[n];
                } else {
                    ushort hu, lu;
                    split_hl(v, hu, lu);
                    Oh[(size_t)m * ldc + n] = hu;
                    Ol[(size_t)m * ldc + n] = lu;
                }
            }
}

// ---------------- K7 v3: logits GEMM, XCD-panel-grouped ordering ------------
__global__ __launch_bounds__(256) void gemm_logits3(
    const unsigned short* __restrict__ Ah, const unsigned short* __restrict__ Al,
    const unsigned short* __restrict__ Bh, const unsigned short* __restrict__ Bl,
    float* __restrict__ out)
{
    const int blk = blockIdx.x;
    const int r = blk & 7, mt = (blk >> 3) & 7, j = blk >> 6;
    const int p = j * 8 + r;
    if (p >= V_ / 128) return;
    const int n0 = p * 128;
    const int m0 = mt * 128;

    __shared__ unsigned short sAh[128 * 64], sAl[128 * 64];
    __shared__ unsigned short sBh[128 * 64], sBl[128 * 64];
    const int tid  = threadIdx.x;
    const int lane = tid & 63;
    const int wv   = tid >> 6;
    const int wr   = wv >> 1, wc = wv & 1;
    f32x4 acc[4][4] = {};

    for (int k0 = 0; k0 < 256; k0 += 64) {
        #pragma unroll
        for (int q = 0; q < 4; ++q) {
            int idx  = q * 256 + tid;
            int row  = idx >> 3;
            int slot = (idx & 7) ^ (row & 7);
            int ldsbase = (q * 256 + wv * 64) * 8;
            size_t ga = (size_t)(m0 + row) * 256 + k0 + slot * 8;
            size_t gb = (size_t)(n0 + row) * 256 + k0 + slot * 8;
            __builtin_amdgcn_global_load_lds(
                (const __attribute__((address_space(1))) void*)(Ah + ga),
                (__attribute__((address_space(3))) void*)(sAh + ldsbase), 16, 0, 0);
            __builtin_amdgcn_global_load_lds(
                (const __attribute__((address_space(1))) void*)(Al + ga),
                (__attribute__((address_space(3))) void*)(sAl + ldsbase), 16, 0, 0);
            __builtin_amdgcn_global_load_lds(
                (const __attribute__((address_space(1))) void*)(Bh + gb),
                (__attribute__((address_space(3))) void*)(sBh + ldsbase), 16, 0, 0);
            __builtin_amdgcn_global_load_lds(
                (const __attribute__((address_space(1))) void*)(Bl + gb),
                (__attribute__((address_space(3))) void*)(sBl + ldsbase), 16, 0, 0);
        }
        __syncthreads();

        #pragma unroll
        for (int ks = 0; ks < 2; ++ks) {
            const int kg = ks * 4 + (lane >> 4);
            bf16x8 afh[4], afl[4], bfh[4], bfl[4];
            #pragma unroll
            for (int mi = 0; mi < 4; ++mi) {
                int row  = wr * 64 + mi * 16 + (lane & 15);
                int slot = kg ^ (row & 7);
                afh[mi] = *(const bf16x8*)&sAh[row * 64 + slot * 8];
                afl[mi] = *(const bf16x8*)&sAl[row * 64 + slot * 8];
            }
            #pragma unroll
            for (int nj = 0; nj < 4; ++nj) {
                int row  = wc * 64 + nj * 16 + (lane & 15);
                int slot = kg ^ (row & 7);
                bfh[nj] = *(const bf16x8*)&sBh[row * 64 + slot * 8];
                bfl[nj] = *(const bf16x8*)&sBl[row * 64 + slot * 8];
            }
            #pragma unroll
            for (int mi = 0; mi < 4; ++mi)
                #pragma unroll
                for (int nj = 0; nj < 4; ++nj) {
                    acc[mi][nj] = __builtin_amdgcn_mfma_f32_16x16x32_bf16(afh[mi], bfh[nj], acc[mi][nj], 0, 0, 0);
                    acc[mi][nj] = __builtin_amdgcn_mfma_f32_16x16x32_bf16(afh[mi], bfl[nj], acc[mi][nj], 0, 0, 0);
                    acc[mi][nj] = __builtin_amdgcn_mfma_f32_16x16x32_bf16(afl[mi], bfh[nj], acc[mi][nj], 0, 0, 0);
                }
        }
        __syncthreads();
    }

    #pragma unroll
    for (int mi = 0; mi < 4; ++mi)
        #pragma unroll
        for (int nj = 0; nj < 4; ++nj)
            #pragma unroll
            for (int rr = 0; rr < 4; ++rr) {
                int m = m0 + wr * 64 + mi * 16 + (lane >> 4) * 4 + rr;
                int n = n0 + wc * 64 + nj * 16 + (lane & 15);
                int orow = (m & 7) * S_ + (m >> 3);
                out[(size_t)orow * V_ + n] = acc[mi][nj][rr];
            }
}

// ---------------- launcher ----------------
extern "C" void kernel_launch(void* const* d_in, const int* in_sizes, int n_in,
                              void* d_out, int out_size, void* d_ws, size_t ws_size,
                              hipStream_t stream)
{
    const int*   ids  = (const int*)d_in[0];
    const float* emb  = (const float*)d_in[1];
    const float* wq   = (const float*)d_in[2];
    const float* bq   = (const float*)d_in[3];
    const float* wk   = (const float*)d_in[4];
    const float* bk   = (const float*)d_in[5];
    const float* Wr   = (const float*)d_in[6];
    const float* Wi   = (const float*)d_in[7];
    const float* Wc   = (const float*)d_in[8];
    const float* bc   = (const float*)d_in[9];
    const float* Wres = (const float*)d_in[10];
    const float* Bres = (const float*)d_in[11];
    const float* Wor  = (const float*)d_in[12];
    const float* Woi  = (const float*)d_in[13];
    const float* Wout = (const float*)d_in[14];
    float* out = (float*)d_out;
    float* ws  = (float*)d_ws;

    // f32 region
    float* xbuf  = ws;                         // 1024*256
    float* qbuf  = xbuf + (size_t)M_ * 256;    // 1024*512
    float* kbuf  = qbuf + (size_t)M_ * 512;    // 1024*512
    float* xc    = kbuf + (size_t)M_ * 512;    // 1024*256
    float* winvT = xc   + (size_t)M_ * 256;    // 65536
    float* bresT = winvT + (size_t)NN_ * D_;   // 65536
    float* hwinv = bresT + (size_t)NN_ * D_;   // 1024*256
    float* hcbuf = hwinv + (size_t)M_ * D_;    // 1024*256
    // ushort region
    unsigned short* us = (unsigned short*)(hcbuf + (size_t)M_ * D_);
    unsigned short* hri_h = us;                       us += (size_t)M_ * 512;
    unsigned short* hri_l = us;                       us += (size_t)M_ * 512;
    unsigned short* G_h   = us;                       us += (size_t)M_ * 768;
    unsigned short* G_l   = us;                       us += (size_t)M_ * 768;
    unsigned short* BB_h  = us;                       us += (size_t)256 * 768;
    unsigned short* BB_l  = us;                       us += (size_t)256 * 768;
    unsigned short* Wc_h  = us;                       us += (size_t)256 * 512;
    unsigned short* Wc_l  = us;                       us += (size_t)256 * 512;
    unsigned short* fus_h = us;                       us += (size_t)M_ * 256;
    unsigned short* fus_l = us;                       us += (size_t)M_ * 256;
    unsigned short* Wo_h  = us;                       us += (size_t)V_ * 256;
    unsigned short* Wo_l  = us;

    // 1. h prep (critical path)
    k_prep_h<<<dim3(M_), dim3(256), 0, stream>>>(ids, emb, hwinv, hcbuf);
    // 2. hscan (8 blocks) + all weight preps on the otherwise-idle 248 CUs
    k_hscan_plus<<<dim3(8584), dim3(256), 0, stream>>>(
        hwinv, hcbuf, Wres, Bres, Wout, Wc, Wr, Wi, Wor, Woi,
        hri_h, hri_l, xbuf, winvT, bresT,
        Wo_h, Wo_l, Wc_h, Wc_l, BB_h, BB_l);
    // 3. Q/K phase vectors
    k_qk<<<dim3(2048), dim3(256), 0, stream>>>(xbuf, wq, bq, wk, bk, qbuf, kbuf);
    // 4. xc = [h_r|h_i] @ Wc^T + bc   (M=1024, N=256, K=512) via MFMA
    gemm_small<<<dim3(2, 8), dim3(256), 0, stream>>>(
        hri_h, hri_l, 512, Wc_h, Wc_l, 512, 512, bc, xc, 256, 0, nullptr, nullptr);
    // 5. attention + resonant, concurrent (disjoint G columns)
    k_attn_res<<<dim3(M_ + M_ / 2), dim3(256), 0, stream>>>(
        qbuf, kbuf, xbuf, xc, winvT, bresT, G_h, G_l);
    // 6. fused = G @ BB^T  (M=1024, N=256, K=768) via MFMA, epilogue hi/lo split
    gemm_small<<<dim3(2, 8), dim3(256), 0, stream>>>(
        G_h, G_l, 768, BB_h, BB_l, 768, 768, nullptr, nullptr, 256, 2, fus_h, fus_l);
    // 7. logits = fused @ Wout^T via bf16x3 MFMA, XCD-panel-grouped grid
    gemm_logits3<<<dim3(2048), dim3(256), 0, stream>>>(fus_h, fus_l, Wo_h, Wo_l, out);
}

// Round 11
// 169.698 us; speedup vs baseline: 1.3413x; 1.1524x over previous
//
#include <hip/hip_runtime.h>
#include <math.h>

// ---------------- constants ----------------
#define PHI_F      ((float)1.6180339887498948482045868343656381177)
#define B_  8
#define S_  128
#define D_  256
#define H_  8
#define DH_ 32
#define NN_ 256
#define V_  32000
#define M_  (B_ * S_)   // 1024 rows, m = t*8 + b

typedef __attribute__((ext_vector_type(4))) float f32x4;
typedef __attribute__((ext_vector_type(8))) short bf16x8;
typedef _Float16 f16x8 __attribute__((ext_vector_type(8)));

__device__ __forceinline__ unsigned short f2bf_rne(float x) {
    unsigned u = __float_as_uint(x);
    unsigned r = (u + 0x7FFFu + ((u >> 16) & 1u)) >> 16;
    return (unsigned short)r;
}

__device__ __forceinline__ void split_hl(float x, unsigned short& h, unsigned short& l) {
    h = f2bf_rne(x);
    float hf = __uint_as_float(((unsigned)h) << 16);
    l = f2bf_rne(__fsub_rn(x, hf));
}

__device__ __forceinline__ unsigned short f2h_bits(float x) {
    _Float16 h = (_Float16)x;     // v_cvt_f16_f32, RNE
    unsigned short u;
    __builtin_memcpy(&u, &h, 2);
    return u;
}

// ---------------- K0: h prep only (critical path for hscan) -----------------
__global__ __launch_bounds__(256) void k_prep_h(
    const int* __restrict__ ids, const float* __restrict__ emb,
    float* __restrict__ hwinv, float* __restrict__ hcbuf)
{
    int m = blockIdx.x, d = threadIdx.x;
    int t = m >> 3, b = m & 7;
    int id = ids[b * S_ + t];
    float w  = emb[(size_t)id * (2 * D_) + d];
    float bt = emb[(size_t)id * (2 * D_) + D_ + d];
    hwinv[(size_t)m * D_ + d] = 1.0f / (1.0f + fabsf(w));
    hcbuf[(size_t)m * D_ + d] = 2.0f * (bt + (float)t * PHI_F);
}

// ---------------- K1: hscan (8 blocks) + all weight preps riding along ------
// blocks [0,8): sequential h-recurrence; [8,264): res prep; [264,392): Wc
// split; [392,584): BB build+split; [584,8584): Wout -> fp16 (single).
__global__ __launch_bounds__(256) void k_hscan_plus(
    const float* __restrict__ winv, const float* __restrict__ cbuf,
    const float* __restrict__ Wres, const float* __restrict__ Bres,
    const float* __restrict__ Wout, const float* __restrict__ Wc,
    const float* __restrict__ Wr, const float* __restrict__ Wi,
    const float* __restrict__ Wor, const float* __restrict__ Woi,
    unsigned short* __restrict__ hri_h, unsigned short* __restrict__ hri_l,
    float* __restrict__ xbuf,
    float* __restrict__ winvT, float* __restrict__ bresT,
    unsigned short* __restrict__ Wo16,
    unsigned short* __restrict__ Wc_h, unsigned short* __restrict__ Wc_l,
    unsigned short* __restrict__ BB_h, unsigned short* __restrict__ BB_l)
{
    const int blk = blockIdx.x;
    const int tid = threadIdx.x;
    if (blk < 8) {
        int b = blk, d = tid;
        float x = 0.f;
        #pragma unroll 4
        for (int t = 0; t < S_; ++t) {
            int m = (t << 3) | b;
            float wi = winv[(size_t)m * D_ + d];
            float c  = cbuf[(size_t)m * D_ + d];
            float u  = fmaf(x, wi, c);
            float s, co;
            __sincosf(u, &s, &co);
            x = co + s;
            ushort hh, hl, sh, sl;
            split_hl(co, hh, hl);
            split_hl(s,  sh, sl);
            hri_h[(size_t)m * 512 + d]       = hh;
            hri_l[(size_t)m * 512 + d]       = hl;
            hri_h[(size_t)m * 512 + 256 + d] = sh;
            hri_l[(size_t)m * 512 + 256 + d] = sl;
            xbuf[(size_t)m * D_ + d]         = x;
        }
    } else if (blk < 264) {
        int i = (blk - 8) * 256 + tid;        // i = n*256+d
        int n = i >> 8, d = i & 255;
        winvT[d * NN_ + n] = 1.0f / (1.0f + fabsf(Wres[i]));
        bresT[d * NN_ + n] = Bres[i];
    } else if (blk < 392) {
        int i = ((blk - 264) * 256 + tid) * 4;    // < 256*512
        float4 v = *(const float4*)&Wc[i];
        float xs[4] = {v.x, v.y, v.z, v.w};
        ushort hs[4], ls[4];
        #pragma unroll
        for (int j = 0; j < 4; ++j) split_hl(xs[j], hs[j], ls[j]);
        *(ushort4*)&Wc_h[i] = make_ushort4(hs[0], hs[1], hs[2], hs[3]);
        *(ushort4*)&Wc_l[i] = make_ushort4(ls[0], ls[1], ls[2], ls[3]);
    } else if (blk < 584) {
        int i = ((blk - 392) * 256 + tid) * 4;    // < 256*768, BB[n][k]
        int n = i / 768, k = i % 768;
        float4 v;
        if (k < 256) {
            float4 a = *(const float4*)&Wr[n * 256 + k];
            float4 b = *(const float4*)&Wi[n * 256 + k];
            v.x = a.x + b.x; v.y = a.y + b.y; v.z = a.z + b.z; v.w = a.w + b.w;
        } else if (k < 512) {
            v = *(const float4*)&Wor[n * 256 + (k - 256)];
        } else {
            v = *(const float4*)&Woi[n * 256 + (k - 512)];
        }
        float xs[4] = {v.x, v.y, v.z, v.w};
        ushort hs[4], ls[4];
        #pragma unroll
        for (int j = 0; j < 4; ++j) split_hl(xs[j], hs[j], ls[j]);
        *(ushort4*)&BB_h[i] = make_ushort4(hs[0], hs[1], hs[2], hs[3]);
        *(ushort4*)&BB_l[i] = make_ushort4(ls[0], ls[1], ls[2], ls[3]);
    } else {
        int i = ((blk - 584) * 256 + tid) * 4;    // < V_*256
        float4 v = *(const float4*)&Wout[i];
        *(ushort4*)&Wo16[i] = make_ushort4(
            f2h_bits(v.x), f2h_bits(v.y), f2h_bits(v.z), f2h_bits(v.w));
    }
}

// ---------------- K2: build Q/K phase vectors (hw sincos, full parallel) ----
__global__ void k_qk(const float* __restrict__ xbuf,
                     const float* __restrict__ wq, const float* __restrict__ bq,
                     const float* __restrict__ wk, const float* __restrict__ bk,
                     float* __restrict__ qbuf, float* __restrict__ kbuf)
{
    int i = blockIdx.x * 256 + threadIdx.x;       // 0 .. 2*half-1
    const int half = S_ * B_ * H_ * DH_;          // 262144
    bool isq = (i < half);
    int r = isq ? i : i - half;
    int j = r & 31;
    int h = (r >> 5) & 7;
    int b = (r >> 8) & 7;
    int t = r >> 11;
    int m = (t << 3) | b;
    float xv = xbuf[(size_t)m * D_ + h * DH_ + j];
    const float* W  = isq ? wq : wk;
    const float* Bv = isq ? bq : bk;
    float inv = 1.0f / (1.0f + fabsf(W[h * DH_ + j]));
    float th = fmaf(xv, inv, Bv[h * DH_ + j]);
    if (isq) th += (float)t * PHI_F;
    float s, c;
    __sincosf(th, &s, &c);
    float* out = isq ? qbuf : kbuf;
    out[(size_t)m * 512 + h * 64 + j]      = c;
    out[(size_t)m * 512 + h * 64 + 32 + j] = s;
}

// ---------------- K3: merged attention (blocks [0,1024)) + resonant ---------
__global__ __launch_bounds__(256) void k_attn_res(
    const float* __restrict__ qbuf, const float* __restrict__ kbuf,
    const float* __restrict__ xbuf, const float* __restrict__ xc,
    const float* __restrict__ winvT, const float* __restrict__ bresT,
    unsigned short* __restrict__ G_h, unsigned short* __restrict__ G_l)
{
    __shared__ float qs[512];
    __shared__ float sc[8][128];
    __shared__ float invdn[8];
    __shared__ float wsum[128];
    const int tid = threadIdx.x;

    if (blockIdx.x < M_) {
        int m = blockIdx.x;
        int t = m >> 3, b = m & 7;
        if (t == 0) {
            G_h[(size_t)m * 768 + tid] = 0;
            G_l[(size_t)m * 768 + tid] = 0;
            return;
        }
        qs[tid]       = qbuf[(size_t)m * 512 + tid];
        qs[tid + 256] = qbuf[(size_t)m * 512 + 256 + tid];
        __syncthreads();
        int h = tid & 7;
        for (int s = tid >> 3; s < t; s += 32) {
            const float* kk = kbuf + (size_t)((s << 3) | b) * 512 + h * 64;
            const float* qq = qs + h * 64;
            float dot = 0.f;
            #pragma unroll
            for (int e = 0; e < 64; ++e) dot += qq[e] * kk[e];
            sc[h][s] = dot * 0.125f;
        }
        __syncthreads();
        int hh = tid >> 5, j = tid & 31;
        float mx = -1e30f;
        for (int s = j; s < t; s += 32) mx = fmaxf(mx, sc[hh][s]);
        #pragma unroll
        for (int o = 16; o; o >>= 1) mx = fmaxf(mx, __shfl_xor(mx, o, 32));
        float dn = 0.f;
        for (int s = j; s < t; s += 32) {
            float e2 = expf(sc[hh][s] - mx);
            sc[hh][s] = e2;
            dn += e2;
        }
        #pragma unroll
        for (int o = 16; o; o >>= 1) dn += __shfl_xor(dn, o, 32);
        if (j == 0) invdn[hh] = 1.0f / dn;
        __syncthreads();
        if (tid < t) {
            float wv = 0.f;
            #pragma unroll
            for (int h2 = 0; h2 < 8; ++h2) wv += sc[h2][tid] * invdn[h2];
            wsum[tid] = wv;
        }
        __syncthreads();
        float a0 = 0.f, a1 = 0.f, a2 = 0.f, a3 = 0.f;
        int s = 0;
        for (; s + 4 <= t; s += 4) {
            a0 += wsum[s + 0] * xbuf[(size_t)(((s + 0) << 3) | b) * D_ + tid];
            a1 += wsum[s + 1] * xbuf[(size_t)(((s + 1) << 3) | b) * D_ + tid];
            a2 += wsum[s + 2] * xbuf[(size_t)(((s + 2) << 3) | b) * D_ + tid];
            a3 += wsum[s + 3] * xbuf[(size_t)(((s + 3) << 3) | b) * D_ + tid];
        }
        for (; s < t; ++s) a0 += wsum[s] * xbuf[(size_t)((s << 3) | b) * D_ + tid];
        float v = (a0 + a1) + (a2 + a3);
        ushort hu, lu;
        split_hl(v, hu, lu);
        G_h[(size_t)m * 768 + tid] = hu;
        G_l[(size_t)m * 768 + tid] = lu;
    } else {
        const int m0 = (blockIdx.x - M_) * 2;
        float* s_xc0 = qs;
        float* s_xc1 = qs + 256;
        s_xc0[tid] = xc[(size_t)m0 * D_ + tid];
        s_xc1[tid] = xc[(size_t)(m0 + 1) * D_ + tid];
        __syncthreads();
        const int n = tid;
        const float tp = __fmul_rn((float)(m0 >> 3), PHI_F);
        float cs0 = 0.f, ss0 = 0.f, cs1 = 0.f, ss1 = 0.f;
        #pragma unroll 4
        for (int d = 0; d < D_; ++d) {
            float wi = winvT[d * NN_ + n];
            float bt = bresT[d * NN_ + n] + tp;
            float th0 = fmaf(s_xc0[d], wi, bt);
            float th1 = fmaf(s_xc1[d], wi, bt);
            cs0 += __cosf(th0); ss0 += __sinf(th0);
            cs1 += __cosf(th1); ss1 += __sinf(th1);
        }
        ushort h0, l0, h1, l1, h2, l2, h3, l3;
        split_hl(cs0, h0, l0); split_hl(ss0, h1, l1);
        split_hl(cs1, h2, l2); split_hl(ss1, h3, l3);
        G_h[(size_t)m0 * 768 + 256 + n] = h0; G_l[(size_t)m0 * 768 + 256 + n] = l0;
        G_h[(size_t)m0 * 768 + 512 + n] = h1; G_l[(size_t)m0 * 768 + 512 + n] = l1;
        G_h[(size_t)(m0 + 1) * 768 + 256 + n] = h2; G_l[(size_t)(m0 + 1) * 768 + 256 + n] = l2;
        G_h[(size_t)(m0 + 1) * 768 + 512 + n] = h3; G_l[(size_t)(m0 + 1) * 768 + 512 + n] = l3;
    }
}

// ---------------- gemm_small: MFMA bf16 3-term, 128x128 tile, generic K -----
// mode 0: f32 out (+bias); mode 2: fp16 out (single array)
__global__ __launch_bounds__(256) void gemm_small(
    const unsigned short* __restrict__ Ah, const unsigned short* __restrict__ Al, int lda,
    const unsigned short* __restrict__ Bh, const unsigned short* __restrict__ Bl, int ldb,
    int K, const float* __restrict__ bias,
    float* __restrict__ outF, int ldc, int mode,
    unsigned short* __restrict__ O16)
{
    __shared__ unsigned short sAh[128 * 64], sAl[128 * 64];
    __shared__ unsigned short sBh[128 * 64], sBl[128 * 64];
    const int n0 = blockIdx.x * 128;
    const int m0 = blockIdx.y * 128;
    const int tid  = threadIdx.x;
    const int lane = tid & 63;
    const int wv   = tid >> 6;
    const int wr   = wv >> 1, wc = wv & 1;
    f32x4 acc[4][4] = {};

    for (int k0 = 0; k0 < K; k0 += 64) {
        #pragma unroll
        for (int q = 0; q < 4; ++q) {
            int idx  = q * 256 + tid;
            int row  = idx >> 3;
            int slot = (idx & 7) ^ (row & 7);
            int ldsbase = (q * 256 + wv * 64) * 8;
            size_t ga = (size_t)(m0 + row) * lda + k0 + slot * 8;
            size_t gb = (size_t)(n0 + row) * ldb + k0 + slot * 8;
            __builtin_amdgcn_global_load_lds(
                (const __attribute__((address_space(1))) void*)(Ah + ga),
                (__attribute__((address_space(3))) void*)(sAh + ldsbase), 16, 0, 0);
            __builtin_amdgcn_global_load_lds(
                (const __attribute__((address_space(1))) void*)(Al + ga),
                (__attribute__((address_space(3))) void*)(sAl + ldsbase), 16, 0, 0);
            __builtin_amdgcn_global_load_lds(
                (const __attribute__((address_space(1))) void*)(Bh + gb),
                (__attribute__((address_space(3))) void*)(sBh + ldsbase), 16, 0, 0);
            __builtin_amdgcn_global_load_lds(
                (const __attribute__((address_space(1))) void*)(Bl + gb),
                (__attribute__((address_space(3))) void*)(sBl + ldsbase), 16, 0, 0);
        }
        __syncthreads();

        #pragma unroll
        for (int ks = 0; ks < 2; ++ks) {
            const int kg = ks * 4 + (lane >> 4);
            bf16x8 afh[4], afl[4], bfh[4], bfl[4];
            #pragma unroll
            for (int mi = 0; mi < 4; ++mi) {
                int row  = wr * 64 + mi * 16 + (lane & 15);
                int slot = kg ^ (row & 7);
                afh[mi] = *(const bf16x8*)&sAh[row * 64 + slot * 8];
                afl[mi] = *(const bf16x8*)&sAl[row * 64 + slot * 8];
            }
            #pragma unroll
            for (int nj = 0; nj < 4; ++nj) {
                int row  = wc * 64 + nj * 16 + (lane & 15);
                int slot = kg ^ (row & 7);
                bfh[nj] = *(const bf16x8*)&sBh[row * 64 + slot * 8];
                bfl[nj] = *(const bf16x8*)&sBl[row * 64 + slot * 8];
            }
            #pragma unroll
            for (int mi = 0; mi < 4; ++mi)
                #pragma unroll
                for (int nj = 0; nj < 4; ++nj) {
                    acc[mi][nj] = __builtin_amdgcn_mfma_f32_16x16x32_bf16(afh[mi], bfh[nj], acc[mi][nj], 0, 0, 0);
                    acc[mi][nj] = __builtin_amdgcn_mfma_f32_16x16x32_bf16(afh[mi], bfl[nj], acc[mi][nj], 0, 0, 0);
                    acc[mi][nj] = __builtin_amdgcn_mfma_f32_16x16x32_bf16(afl[mi], bfh[nj], acc[mi][nj], 0, 0, 0);
                }
        }
        __syncthreads();
    }

    #pragma unroll
    for (int mi = 0; mi < 4; ++mi)
        #pragma unroll
        for (int nj = 0; nj < 4; ++nj)
            #pragma unroll
            for (int r = 0; r < 4; ++r) {
                int m = m0 + wr * 64 + mi * 16 + (lane >> 4) * 4 + r;
                int n = n0 + wc * 64 + nj * 16 + (lane & 15);
                float v = acc[mi][nj][r];
                if (mode == 0) {
                    outF[(size_t)m * ldc + n] = v + bias[n];
                } else {
                    O16[(size_t)m * ldc + n] = f2h_bits(v);
                }
            }
}

// ---------------- K7 v4: logits GEMM, fp16 single-term, XCD-panel-grouped ---
__global__ __launch_bounds__(256) void gemm_logits4(
    const unsigned short* __restrict__ A16, const unsigned short* __restrict__ B16,
    float* __restrict__ out)
{
    const int blk = blockIdx.x;
    const int r = blk & 7, mt = (blk >> 3) & 7, j = blk >> 6;
    const int p = j * 8 + r;
    if (p >= V_ / 128) return;
    const int n0 = p * 128;
    const int m0 = mt * 128;

    __shared__ unsigned short sA[128 * 64], sB[128 * 64];
    const int tid  = threadIdx.x;
    const int lane = tid & 63;
    const int wv   = tid >> 6;
    const int wr   = wv >> 1, wc = wv & 1;
    f32x4 acc[4][4] = {};

    for (int k0 = 0; k0 < 256; k0 += 64) {
        #pragma unroll
        for (int q = 0; q < 4; ++q) {
            int idx  = q * 256 + tid;
            int row  = idx >> 3;
            int slot = (idx & 7) ^ (row & 7);
            int ldsbase = (q * 256 + wv * 64) * 8;
            size_t ga = (size_t)(m0 + row) * 256 + k0 + slot * 8;
            size_t gb = (size_t)(n0 + row) * 256 + k0 + slot * 8;
            __builtin_amdgcn_global_load_lds(
                (const __attribute__((address_space(1))) void*)(A16 + ga),
                (__attribute__((address_space(3))) void*)(sA + ldsbase), 16, 0, 0);
            __builtin_amdgcn_global_load_lds(
                (const __attribute__((address_space(1))) void*)(B16 + gb),
                (__attribute__((address_space(3))) void*)(sB + ldsbase), 16, 0, 0);
        }
        __syncthreads();

        #pragma unroll
        for (int ks = 0; ks < 2; ++ks) {
            const int kg = ks * 4 + (lane >> 4);
            f16x8 af[4], bf[4];
            #pragma unroll
            for (int mi = 0; mi < 4; ++mi) {
                int row  = wr * 64 + mi * 16 + (lane & 15);
                int slot = kg ^ (row & 7);
                af[mi] = *(const f16x8*)&sA[row * 64 + slot * 8];
            }
            #pragma unroll
            for (int nj = 0; nj < 4; ++nj) {
                int row  = wc * 64 + nj * 16 + (lane & 15);
                int slot = kg ^ (row & 7);
                bf[nj] = *(const f16x8*)&sB[row * 64 + slot * 8];
            }
            #pragma unroll
            for (int mi = 0; mi < 4; ++mi)
                #pragma unroll
                for (int nj = 0; nj < 4; ++nj)
                    acc[mi][nj] = __builtin_amdgcn_mfma_f32_16x16x32_f16(af[mi], bf[nj], acc[mi][nj], 0, 0, 0);
        }
        __syncthreads();
    }

    #pragma unroll
    for (int mi = 0; mi < 4; ++mi)
        #pragma unroll
        for (int nj = 0; nj < 4; ++nj)
            #pragma unroll
            for (int rr = 0; rr < 4; ++rr) {
                int m = m0 + wr * 64 + mi * 16 + (lane >> 4) * 4 + rr;
                int n = n0 + wc * 64 + nj * 16 + (lane & 15);
                int orow = (m & 7) * S_ + (m >> 3);
                out[(size_t)orow * V_ + n] = acc[mi][nj][rr];
            }
}

// ---------------- launcher ----------------
extern "C" void kernel_launch(void* const* d_in, const int* in_sizes, int n_in,
                              void* d_out, int out_size, void* d_ws, size_t ws_size,
                              hipStream_t stream)
{
    const int*   ids  = (const int*)d_in[0];
    const float* emb  = (const float*)d_in[1];
    const float* wq   = (const float*)d_in[2];
    const float* bq   = (const float*)d_in[3];
    const float* wk   = (const float*)d_in[4];
    const float* bk   = (const float*)d_in[5];
    const float* Wr   = (const float*)d_in[6];
    const float* Wi   = (const float*)d_in[7];
    const float* Wc   = (const float*)d_in[8];
    const float* bc   = (const float*)d_in[9];
    const float* Wres = (const float*)d_in[10];
    const float* Bres = (const float*)d_in[11];
    const float* Wor  = (const float*)d_in[12];
    const float* Woi  = (const float*)d_in[13];
    const float* Wout = (const float*)d_in[14];
    float* out = (float*)d_out;
    float* ws  = (float*)d_ws;

    // f32 region
    float* xbuf  = ws;                         // 1024*256
    float* qbuf  = xbuf + (size_t)M_ * 256;    // 1024*512
    float* kbuf  = qbuf + (size_t)M_ * 512;    // 1024*512
    float* xc    = kbuf + (size_t)M_ * 512;    // 1024*256
    float* winvT = xc   + (size_t)M_ * 256;    // 65536
    float* bresT = winvT + (size_t)NN_ * D_;   // 65536
    float* hwinv = bresT + (size_t)NN_ * D_;   // 1024*256
    float* hcbuf = hwinv + (size_t)M_ * D_;    // 1024*256
    // ushort region
    unsigned short* us = (unsigned short*)(hcbuf + (size_t)M_ * D_);
    unsigned short* hri_h = us;                       us += (size_t)M_ * 512;
    unsigned short* hri_l = us;                       us += (size_t)M_ * 512;
    unsigned short* G_h   = us;                       us += (size_t)M_ * 768;
    unsigned short* G_l   = us;                       us += (size_t)M_ * 768;
    unsigned short* BB_h  = us;                       us += (size_t)256 * 768;
    unsigned short* BB_l  = us;                       us += (size_t)256 * 768;
    unsigned short* Wc_h  = us;                       us += (size_t)256 * 512;
    unsigned short* Wc_l  = us;                       us += (size_t)256 * 512;
    unsigned short* fus16 = us;                       us += (size_t)M_ * 256;
    unsigned short* Wo16  = us;

    // 1. h prep (critical path)
    k_prep_h<<<dim3(M_), dim3(256), 0, stream>>>(ids, emb, hwinv, hcbuf);
    // 2. hscan (8 blocks) + all weight preps on the otherwise-idle 248 CUs
    k_hscan_plus<<<dim3(8584), dim3(256), 0, stream>>>(
        hwinv, hcbuf, Wres, Bres, Wout, Wc, Wr, Wi, Wor, Woi,
        hri_h, hri_l, xbuf, winvT, bresT,
        Wo16, Wc_h, Wc_l, BB_h, BB_l);
    // 3. Q/K phase vectors
    k_qk<<<dim3(2048), dim3(256), 0, stream>>>(xbuf, wq, bq, wk, bk, qbuf, kbuf);
    // 4. xc = [h_r|h_i] @ Wc^T + bc   (M=1024, N=256, K=512) via MFMA
    gemm_small<<<dim3(2, 8), dim3(256), 0, stream>>>(
        hri_h, hri_l, 512, Wc_h, Wc_l, 512, 512, bc, xc, 256, 0, nullptr);
    // 5. attention + resonant, concurrent (disjoint G columns)
    k_attn_res<<<dim3(M_ + M_ / 2), dim3(256), 0, stream>>>(
        qbuf, kbuf, xbuf, xc, winvT, bresT, G_h, G_l);
    // 6. fused = G @ BB^T  (M=1024, N=256, K=768) via MFMA, fp16 epilogue
    gemm_small<<<dim3(2, 8), dim3(256), 0, stream>>>(
        G_h, G_l, 768, BB_h, BB_l, 768, 768, nullptr, nullptr, 256, 2, fus16);
    // 7. logits = fused @ Wout^T via single-term fp16 MFMA
    gemm_logits4<<<dim3(2048), dim3(256), 0, stream>>>(fus16, Wo16, out);
}

// Round 12
// 161.147 us; speedup vs baseline: 1.4125x; 1.0531x over previous
//
#include <hip/hip_runtime.h>
#include <math.h>

// ---------------- constants ----------------
#define PHI_F      ((float)1.6180339887498948482045868343656381177)
#define B_  8
#define S_  128
#define D_  256
#define H_  8
#define DH_ 32
#define NN_ 256
#define V_  32000
#define M_  (B_ * S_)   // 1024 rows, m = t*8 + b

typedef __attribute__((ext_vector_type(4))) float f32x4;
typedef __attribute__((ext_vector_type(8))) short bf16x8;
typedef _Float16 f16x8 __attribute__((ext_vector_type(8)));

__device__ __forceinline__ unsigned short f2bf_rne(float x) {
    unsigned u = __float_as_uint(x);
    unsigned r = (u + 0x7FFFu + ((u >> 16) & 1u)) >> 16;
    return (unsigned short)r;
}

__device__ __forceinline__ void split_hl(float x, unsigned short& h, unsigned short& l) {
    h = f2bf_rne(x);
    float hf = __uint_as_float(((unsigned)h) << 16);
    l = f2bf_rne(__fsub_rn(x, hf));
}

__device__ __forceinline__ unsigned short f2h_bits(float x) {
    _Float16 h = (_Float16)x;     // v_cvt_f16_f32, RNE
    unsigned short u;
    __builtin_memcpy(&u, &h, 2);
    return u;
}

// ---------------- K0: h prep only (critical path for hscan) -----------------
__global__ __launch_bounds__(256) void k_prep_h(
    const int* __restrict__ ids, const float* __restrict__ emb,
    float* __restrict__ hwinv, float* __restrict__ hcbuf)
{
    int m = blockIdx.x, d = threadIdx.x;
    int t = m >> 3, b = m & 7;
    int id = ids[b * S_ + t];
    float w  = emb[(size_t)id * (2 * D_) + d];
    float bt = emb[(size_t)id * (2 * D_) + D_ + d];
    hwinv[(size_t)m * D_ + d] = 1.0f / (1.0f + fabsf(w));
    hcbuf[(size_t)m * D_ + d] = 2.0f * (bt + (float)t * PHI_F);
}

// ---------------- K1: hscan (8 blocks) + all weight preps riding along ------
// [0,8): h-recurrence; [8,264): res prep; [264,392): Wc split;
// [392,584): BB build+split; [584,4584): Wout -> fp16, 8 elems/thread.
__global__ __launch_bounds__(256) void k_hscan_plus(
    const float* __restrict__ winv, const float* __restrict__ cbuf,
    const float* __restrict__ Wres, const float* __restrict__ Bres,
    const float* __restrict__ Wout, const float* __restrict__ Wc,
    const float* __restrict__ Wr, const float* __restrict__ Wi,
    const float* __restrict__ Wor, const float* __restrict__ Woi,
    unsigned short* __restrict__ hri_h, unsigned short* __restrict__ hri_l,
    float* __restrict__ xbuf,
    float* __restrict__ winvT, float* __restrict__ bresT,
    unsigned short* __restrict__ Wo16,
    unsigned short* __restrict__ Wc_h, unsigned short* __restrict__ Wc_l,
    unsigned short* __restrict__ BB_h, unsigned short* __restrict__ BB_l)
{
    const int blk = blockIdx.x;
    const int tid = threadIdx.x;
    if (blk < 8) {
        int b = blk, d = tid;
        float x = 0.f;
        #pragma unroll 4
        for (int t = 0; t < S_; ++t) {
            int m = (t << 3) | b;
            float wi = winv[(size_t)m * D_ + d];
            float c  = cbuf[(size_t)m * D_ + d];
            float u  = fmaf(x, wi, c);
            float s, co;
            __sincosf(u, &s, &co);
            x = co + s;
            ushort hh, hl, sh, sl;
            split_hl(co, hh, hl);
            split_hl(s,  sh, sl);
            hri_h[(size_t)m * 512 + d]       = hh;
            hri_l[(size_t)m * 512 + d]       = hl;
            hri_h[(size_t)m * 512 + 256 + d] = sh;
            hri_l[(size_t)m * 512 + 256 + d] = sl;
            xbuf[(size_t)m * D_ + d]         = x;
        }
    } else if (blk < 264) {
        int i = (blk - 8) * 256 + tid;        // i = n*256+d
        int n = i >> 8, d = i & 255;
        winvT[d * NN_ + n] = 1.0f / (1.0f + fabsf(Wres[i]));
        bresT[d * NN_ + n] = Bres[i];
    } else if (blk < 392) {
        int i = ((blk - 264) * 256 + tid) * 4;    // < 256*512
        float4 v = *(const float4*)&Wc[i];
        float xs[4] = {v.x, v.y, v.z, v.w};
        ushort hs[4], ls[4];
        #pragma unroll
        for (int j = 0; j < 4; ++j) split_hl(xs[j], hs[j], ls[j]);
        *(ushort4*)&Wc_h[i] = make_ushort4(hs[0], hs[1], hs[2], hs[3]);
        *(ushort4*)&Wc_l[i] = make_ushort4(ls[0], ls[1], ls[2], ls[3]);
    } else if (blk < 584) {
        int i = ((blk - 392) * 256 + tid) * 4;    // < 256*768, BB[n][k]
        int n = i / 768, k = i % 768;
        float4 v;
        if (k < 256) {
            float4 a = *(const float4*)&Wr[n * 256 + k];
            float4 b = *(const float4*)&Wi[n * 256 + k];
            v.x = a.x + b.x; v.y = a.y + b.y; v.z = a.z + b.z; v.w = a.w + b.w;
        } else if (k < 512) {
            v = *(const float4*)&Wor[n * 256 + (k - 256)];
        } else {
            v = *(const float4*)&Woi[n * 256 + (k - 512)];
        }
        float xs[4] = {v.x, v.y, v.z, v.w};
        ushort hs[4], ls[4];
        #pragma unroll
        for (int j = 0; j < 4; ++j) split_hl(xs[j], hs[j], ls[j]);
        *(ushort4*)&BB_h[i] = make_ushort4(hs[0], hs[1], hs[2], hs[3]);
        *(ushort4*)&BB_l[i] = make_ushort4(ls[0], ls[1], ls[2], ls[3]);
    } else {
        int i = ((blk - 584) * 256 + tid) * 8;    // < V_*256, 8/thread
        float4 v0 = *(const float4*)&Wout[i];
        float4 v1 = *(const float4*)&Wout[i + 4];
        ushort4 o0 = make_ushort4(f2h_bits(v0.x), f2h_bits(v0.y), f2h_bits(v0.z), f2h_bits(v0.w));
        ushort4 o1 = make_ushort4(f2h_bits(v1.x), f2h_bits(v1.y), f2h_bits(v1.z), f2h_bits(v1.w));
        *(ushort4*)&Wo16[i]     = o0;
        *(ushort4*)&Wo16[i + 4] = o1;
    }
}

// ---------------- K2: merged qk (blocks [16,2064)) + gemm1 ([0,16)) ---------
// Both depend only on hscan output; mutually independent; one launch.
__global__ __launch_bounds__(256) void k_qk_gemm1(
    const float* __restrict__ xbuf,
    const float* __restrict__ wq, const float* __restrict__ bq,
    const float* __restrict__ wk, const float* __restrict__ bk,
    float* __restrict__ qbuf, float* __restrict__ kbuf,
    const unsigned short* __restrict__ Ah, const unsigned short* __restrict__ Al,
    const unsigned short* __restrict__ Bh, const unsigned short* __restrict__ Bl,
    const float* __restrict__ bias, float* __restrict__ xc)
{
    __shared__ unsigned short sAh[128 * 64], sAl[128 * 64];
    __shared__ unsigned short sBh[128 * 64], sBl[128 * 64];
    const int tid = threadIdx.x;

    if (blockIdx.x >= 16) {
        // ---------------- qk ----------------
        int i = (blockIdx.x - 16) * 256 + tid;        // 0 .. 2*half-1
        const int half = S_ * B_ * H_ * DH_;          // 262144
        bool isq = (i < half);
        int r = isq ? i : i - half;
        int j = r & 31;
        int h = (r >> 5) & 7;
        int b = (r >> 8) & 7;
        int t = r >> 11;
        int m = (t << 3) | b;
        float xv = xbuf[(size_t)m * D_ + h * DH_ + j];
        const float* W  = isq ? wq : wk;
        const float* Bv = isq ? bq : bk;
        float inv = 1.0f / (1.0f + fabsf(W[h * DH_ + j]));
        float th = fmaf(xv, inv, Bv[h * DH_ + j]);
        if (isq) th += (float)t * PHI_F;
        float s, c;
        __sincosf(th, &s, &c);
        float* out = isq ? qbuf : kbuf;
        out[(size_t)m * 512 + h * 64 + j]      = c;
        out[(size_t)m * 512 + h * 64 + 32 + j] = s;
        return;
    }

    // ---------------- gemm1: xc = [h_r|h_i] @ Wc^T + bc, K=512 -------------
    const int n0 = (blockIdx.x & 1) * 128;
    const int m0 = (blockIdx.x >> 1) * 128;
    const int lane = tid & 63;
    const int wv   = tid >> 6;
    const int wr   = wv >> 1, wc = wv & 1;
    f32x4 acc[4][4] = {};

    for (int k0 = 0; k0 < 512; k0 += 64) {
        #pragma unroll
        for (int q = 0; q < 4; ++q) {
            int idx  = q * 256 + tid;
            int row  = idx >> 3;
            int slot = (idx & 7) ^ (row & 7);
            int ldsbase = (q * 256 + wv * 64) * 8;
            size_t ga = (size_t)(m0 + row) * 512 + k0 + slot * 8;
            size_t gb = (size_t)(n0 + row) * 512 + k0 + slot * 8;
            __builtin_amdgcn_global_load_lds(
                (const __attribute__((address_space(1))) void*)(Ah + ga),
                (__attribute__((address_space(3))) void*)(sAh + ldsbase), 16, 0, 0);
            __builtin_amdgcn_global_load_lds(
                (const __attribute__((address_space(1))) void*)(Al + ga),
                (__attribute__((address_space(3))) void*)(sAl + ldsbase), 16, 0, 0);
            __builtin_amdgcn_global_load_lds(
                (const __attribute__((address_space(1))) void*)(Bh + gb),
                (__attribute__((address_space(3))) void*)(sBh + ldsbase), 16, 0, 0);
            __builtin_amdgcn_global_load_lds(
                (const __attribute__((address_space(1))) void*)(Bl + gb),
                (__attribute__((address_space(3))) void*)(sBl + ldsbase), 16, 0, 0);
        }
        __syncthreads();

        #pragma unroll
        for (int ks = 0; ks < 2; ++ks) {
            const int kg = ks * 4 + (lane >> 4);
            bf16x8 afh[4], afl[4], bfh[4], bfl[4];
            #pragma unroll
            for (int mi = 0; mi < 4; ++mi) {
                int row  = wr * 64 + mi * 16 + (lane & 15);
                int slot = kg ^ (row & 7);
                afh[mi] = *(const bf16x8*)&sAh[row * 64 + slot * 8];
                afl[mi] = *(const bf16x8*)&sAl[row * 64 + slot * 8];
            }
            #pragma unroll
            for (int nj = 0; nj < 4; ++nj) {
                int row  = wc * 64 + nj * 16 + (lane & 15);
                int slot = kg ^ (row & 7);
                bfh[nj] = *(const bf16x8*)&sBh[row * 64 + slot * 8];
                bfl[nj] = *(const bf16x8*)&sBl[row * 64 + slot * 8];
            }
            #pragma unroll
            for (int mi = 0; mi < 4; ++mi)
                #pragma unroll
                for (int nj = 0; nj < 4; ++nj) {
                    acc[mi][nj] = __builtin_amdgcn_mfma_f32_16x16x32_bf16(afh[mi], bfh[nj], acc[mi][nj], 0, 0, 0);
                    acc[mi][nj] = __builtin_amdgcn_mfma_f32_16x16x32_bf16(afh[mi], bfl[nj], acc[mi][nj], 0, 0, 0);
                    acc[mi][nj] = __builtin_amdgcn_mfma_f32_16x16x32_bf16(afl[mi], bfh[nj], acc[mi][nj], 0, 0, 0);
                }
        }
        __syncthreads();
    }

    #pragma unroll
    for (int mi = 0; mi < 4; ++mi)
        #pragma unroll
        for (int nj = 0; nj < 4; ++nj)
            #pragma unroll
            for (int r = 0; r < 4; ++r) {
                int m = m0 + wr * 64 + mi * 16 + (lane >> 4) * 4 + r;
                int n = n0 + wc * 64 + nj * 16 + (lane & 15);
                xc[(size_t)m * 256 + n] = acc[mi][nj][r] + bias[n];
            }
}

// ---------------- K3: merged attention (blocks [0,1024)) + resonant ---------
__global__ __launch_bounds__(256) void k_attn_res(
    const float* __restrict__ qbuf, const float* __restrict__ kbuf,
    const float* __restrict__ xbuf, const float* __restrict__ xc,
    const float* __restrict__ winvT, const float* __restrict__ bresT,
    unsigned short* __restrict__ G_h, unsigned short* __restrict__ G_l)
{
    __shared__ float qs[512];
    __shared__ float sc[8][128];
    __shared__ float invdn[8];
    __shared__ float wsum[128];
    const int tid = threadIdx.x;

    if (blockIdx.x < M_) {
        int m = blockIdx.x;
        int t = m >> 3, b = m & 7;
        if (t == 0) {
            G_h[(size_t)m * 768 + tid] = 0;
            G_l[(size_t)m * 768 + tid] = 0;
            return;
        }
        qs[tid]       = qbuf[(size_t)m * 512 + tid];
        qs[tid + 256] = qbuf[(size_t)m * 512 + 256 + tid];
        __syncthreads();
        int h = tid & 7;
        for (int s = tid >> 3; s < t; s += 32) {
            const float* kk = kbuf + (size_t)((s << 3) | b) * 512 + h * 64;
            const float* qq = qs + h * 64;
            float dot = 0.f;
            #pragma unroll
            for (int e = 0; e < 64; ++e) dot += qq[e] * kk[e];
            sc[h][s] = dot * 0.125f;
        }
        __syncthreads();
        int hh = tid >> 5, j = tid & 31;
        float mx = -1e30f;
        for (int s = j; s < t; s += 32) mx = fmaxf(mx, sc[hh][s]);
        #pragma unroll
        for (int o = 16; o; o >>= 1) mx = fmaxf(mx, __shfl_xor(mx, o, 32));
        float dn = 0.f;
        for (int s = j; s < t; s += 32) {
            float e2 = expf(sc[hh][s] - mx);
            sc[hh][s] = e2;
            dn += e2;
        }
        #pragma unroll
        for (int o = 16; o; o >>= 1) dn += __shfl_xor(dn, o, 32);
        if (j == 0) invdn[hh] = 1.0f / dn;
        __syncthreads();
        if (tid < t) {
            float wv = 0.f;
            #pragma unroll
            for (int h2 = 0; h2 < 8; ++h2) wv += sc[h2][tid] * invdn[h2];
            wsum[tid] = wv;
        }
        __syncthreads();
        float a0 = 0.f, a1 = 0.f, a2 = 0.f, a3 = 0.f;
        int s = 0;
        for (; s + 4 <= t; s += 4) {
            a0 += wsum[s + 0] * xbuf[(size_t)(((s + 0) << 3) | b) * D_ + tid];
            a1 += wsum[s + 1] * xbuf[(size_t)(((s + 1) << 3) | b) * D_ + tid];
            a2 += wsum[s + 2] * xbuf[(size_t)(((s + 2) << 3) | b) * D_ + tid];
            a3 += wsum[s + 3] * xbuf[(size_t)(((s + 3) << 3) | b) * D_ + tid];
        }
        for (; s < t; ++s) a0 += wsum[s] * xbuf[(size_t)((s << 3) | b) * D_ + tid];
        float v = (a0 + a1) + (a2 + a3);
        ushort hu, lu;
        split_hl(v, hu, lu);
        G_h[(size_t)m * 768 + tid] = hu;
        G_l[(size_t)m * 768 + tid] = lu;
    } else {
        const int m0 = (blockIdx.x - M_) * 2;
        float* s_xc0 = qs;
        float* s_xc1 = qs + 256;
        s_xc0[tid] = xc[(size_t)m0 * D_ + tid];
        s_xc1[tid] = xc[(size_t)(m0 + 1) * D_ + tid];
        __syncthreads();
        const int n = tid;
        const float tp = __fmul_rn((float)(m0 >> 3), PHI_F);
        float cs0 = 0.f, ss0 = 0.f, cs1 = 0.f, ss1 = 0.f;
        #pragma unroll 4
        for (int d = 0; d < D_; ++d) {
            float wi = winvT[d * NN_ + n];
            float bt = bresT[d * NN_ + n] + tp;
            float th0 = fmaf(s_xc0[d], wi, bt);
            float th1 = fmaf(s_xc1[d], wi, bt);
            cs0 += __cosf(th0); ss0 += __sinf(th0);
            cs1 += __cosf(th1); ss1 += __sinf(th1);
        }
        ushort h0, l0, h1, l1, h2, l2, h3, l3;
        split_hl(cs0, h0, l0); split_hl(ss0, h1, l1);
        split_hl(cs1, h2, l2); split_hl(ss1, h3, l3);
        G_h[(size_t)m0 * 768 + 256 + n] = h0; G_l[(size_t)m0 * 768 + 256 + n] = l0;
        G_h[(size_t)m0 * 768 + 512 + n] = h1; G_l[(size_t)m0 * 768 + 512 + n] = l1;
        G_h[(size_t)(m0 + 1) * 768 + 256 + n] = h2; G_l[(size_t)(m0 + 1) * 768 + 256 + n] = l2;
        G_h[(size_t)(m0 + 1) * 768 + 512 + n] = h3; G_l[(size_t)(m0 + 1) * 768 + 512 + n] = l3;
    }
}

// ---------------- gemm2: MFMA bf16 3-term, K=768, fp16 epilogue -------------
__global__ __launch_bounds__(256) void gemm_fused(
    const unsigned short* __restrict__ Ah, const unsigned short* __restrict__ Al,
    const unsigned short* __restrict__ Bh, const unsigned short* __restrict__ Bl,
    unsigned short* __restrict__ O16)
{
    __shared__ unsigned short sAh[128 * 64], sAl[128 * 64];
    __shared__ unsigned short sBh[128 * 64], sBl[128 * 64];
    const int n0 = blockIdx.x * 128;
    const int m0 = blockIdx.y * 128;
    const int tid  = threadIdx.x;
    const int lane = tid & 63;
    const int wv   = tid >> 6;
    const int wr   = wv >> 1, wc = wv & 1;
    f32x4 acc[4][4] = {};

    for (int k0 = 0; k0 < 768; k0 += 64) {
        #pragma unroll
        for (int q = 0; q < 4; ++q) {
            int idx  = q * 256 + tid;
            int row  = idx >> 3;
            int slot = (idx & 7) ^ (row & 7);
            int ldsbase = (q * 256 + wv * 64) * 8;
            size_t ga = (size_t)(m0 + row) * 768 + k0 + slot * 8;
            size_t gb = (size_t)(n0 + row) * 768 + k0 + slot * 8;
            __builtin_amdgcn_global_load_lds(
                (const __attribute__((address_space(1))) void*)(Ah + ga),
                (__attribute__((address_space(3))) void*)(sAh + ldsbase), 16, 0, 0);
            __builtin_amdgcn_global_load_lds(
                (const __attribute__((address_space(1))) void*)(Al + ga),
                (__attribute__((address_space(3))) void*)(sAl + ldsbase), 16, 0, 0);
            __builtin_amdgcn_global_load_lds(
                (const __attribute__((address_space(1))) void*)(Bh + gb),
                (__attribute__((address_space(3))) void*)(sBh + ldsbase), 16, 0, 0);
            __builtin_amdgcn_global_load_lds(
                (const __attribute__((address_space(1))) void*)(Bl + gb),
                (__attribute__((address_space(3))) void*)(sBl + ldsbase), 16, 0, 0);
        }
        __syncthreads();

        #pragma unroll
        for (int ks = 0; ks < 2; ++ks) {
            const int kg = ks * 4 + (lane >> 4);
            bf16x8 afh[4], afl[4], bfh[4], bfl[4];
            #pragma unroll
            for (int mi = 0; mi < 4; ++mi) {
                int row  = wr * 64 + mi * 16 + (lane & 15);
                int slot = kg ^ (row & 7);
                afh[mi] = *(const bf16x8*)&sAh[row * 64 + slot * 8];
                afl[mi] = *(const bf16x8*)&sAl[row * 64 + slot * 8];
            }
            #pragma unroll
            for (int nj = 0; nj < 4; ++nj) {
                int row  = wc * 64 + nj * 16 + (lane & 15);
                int slot = kg ^ (row & 7);
                bfh[nj] = *(const bf16x8*)&sBh[row * 64 + slot * 8];
                bfl[nj] = *(const bf16x8*)&sBl[row * 64 + slot * 8];
            }
            #pragma unroll
            for (int mi = 0; mi < 4; ++mi)
                #pragma unroll
                for (int nj = 0; nj < 4; ++nj) {
                    acc[mi][nj] = __builtin_amdgcn_mfma_f32_16x16x32_bf16(afh[mi], bfh[nj], acc[mi][nj], 0, 0, 0);
                    acc[mi][nj] = __builtin_amdgcn_mfma_f32_16x16x32_bf16(afh[mi], bfl[nj], acc[mi][nj], 0, 0, 0);
                    acc[mi][nj] = __builtin_amdgcn_mfma_f32_16x16x32_bf16(afl[mi], bfh[nj], acc[mi][nj], 0, 0, 0);
                }
        }
        __syncthreads();
    }

    #pragma unroll
    for (int mi = 0; mi < 4; ++mi)
        #pragma unroll
        for (int nj = 0; nj < 4; ++nj)
            #pragma unroll
            for (int r = 0; r < 4; ++r) {
                int m = m0 + wr * 64 + mi * 16 + (lane >> 4) * 4 + r;
                int n = n0 + wc * 64 + nj * 16 + (lane & 15);
                O16[(size_t)m * 256 + n] = f2h_bits(acc[mi][nj][r]);
            }
}

// ---------------- K7 v4: logits GEMM, fp16 single-term, XCD-panel-grouped ---
__global__ __launch_bounds__(256) void gemm_logits4(
    const unsigned short* __restrict__ A16, const unsigned short* __restrict__ B16,
    float* __restrict__ out)
{
    const int blk = blockIdx.x;
    const int r = blk & 7, mt = (blk >> 3) & 7, j = blk >> 6;
    const int p = j * 8 + r;
    if (p >= V_ / 128) return;
    const int n0 = p * 128;
    const int m0 = mt * 128;

    __shared__ unsigned short sA[128 * 64], sB[128 * 64];
    const int tid  = threadIdx.x;
    const int lane = tid & 63;
    const int wv   = tid >> 6;
    const int wr   = wv >> 1, wc = wv & 1;
    f32x4 acc[4][4] = {};

    for (int k0 = 0; k0 < 256; k0 += 64) {
        #pragma unroll
        for (int q = 0; q < 4; ++q) {
            int idx  = q * 256 + tid;
            int row  = idx >> 3;
            int slot = (idx & 7) ^ (row & 7);
            int ldsbase = (q * 256 + wv * 64) * 8;
            size_t ga = (size_t)(m0 + row) * 256 + k0 + slot * 8;
            size_t gb = (size_t)(n0 + row) * 256 + k0 + slot * 8;
            __builtin_amdgcn_global_load_lds(
                (const __attribute__((address_space(1))) void*)(A16 + ga),
                (__attribute__((address_space(3))) void*)(sA + ldsbase), 16, 0, 0);
            __builtin_amdgcn_global_load_lds(
                (const __attribute__((address_space(1))) void*)(B16 + gb),
                (__attribute__((address_space(3))) void*)(sB + ldsbase), 16, 0, 0);
        }
        __syncthreads();

        #pragma unroll
        for (int ks = 0; ks < 2; ++ks) {
            const int kg = ks * 4 + (lane >> 4);
            f16x8 af[4], bf[4];
            #pragma unroll
            for (int mi = 0; mi < 4; ++mi) {
                int row  = wr * 64 + mi * 16 + (lane & 15);
                int slot = kg ^ (row & 7);
                af[mi] = *(const f16x8*)&sA[row * 64 + slot * 8];
            }
            #pragma unroll
            for (int nj = 0; nj < 4; ++nj) {
                int row  = wc * 64 + nj * 16 + (lane & 15);
                int slot = kg ^ (row & 7);
                bf[nj] = *(const f16x8*)&sB[row * 64 + slot * 8];
            }
            #pragma unroll
            for (int mi = 0; mi < 4; ++mi)
                #pragma unroll
                for (int nj = 0; nj < 4; ++nj)
                    acc[mi][nj] = __builtin_amdgcn_mfma_f32_16x16x32_f16(af[mi], bf[nj], acc[mi][nj], 0, 0, 0);
        }
        __syncthreads();
    }

    #pragma unroll
    for (int mi = 0; mi < 4; ++mi)
        #pragma unroll
        for (int nj = 0; nj < 4; ++nj)
            #pragma unroll
            for (int rr = 0; rr < 4; ++rr) {
                int m = m0 + wr * 64 + mi * 16 + (lane >> 4) * 4 + rr;
                int n = n0 + wc * 64 + nj * 16 + (lane & 15);
                int orow = (m & 7) * S_ + (m >> 3);
                out[(size_t)orow * V_ + n] = acc[mi][nj][rr];
            }
}

// ---------------- launcher ----------------
extern "C" void kernel_launch(void* const* d_in, const int* in_sizes, int n_in,
                              void* d_out, int out_size, void* d_ws, size_t ws_size,
                              hipStream_t stream)
{
    const int*   ids  = (const int*)d_in[0];
    const float* emb  = (const float*)d_in[1];
    const float* wq   = (const float*)d_in[2];
    const float* bq   = (const float*)d_in[3];
    const float* wk   = (const float*)d_in[4];
    const float* bk   = (const float*)d_in[5];
    const float* Wr   = (const float*)d_in[6];
    const float* Wi   = (const float*)d_in[7];
    const float* Wc   = (const float*)d_in[8];
    const float* bc   = (const float*)d_in[9];
    const float* Wres = (const float*)d_in[10];
    const float* Bres = (const float*)d_in[11];
    const float* Wor  = (const float*)d_in[12];
    const float* Woi  = (const float*)d_in[13];
    const float* Wout = (const float*)d_in[14];
    float* out = (float*)d_out;
    float* ws  = (float*)d_ws;

    // f32 region
    float* xbuf  = ws;                         // 1024*256
    float* qbuf  = xbuf + (size_t)M_ * 256;    // 1024*512
    float* kbuf  = qbuf + (size_t)M_ * 512;    // 1024*512
    float* xc    = kbuf + (size_t)M_ * 512;    // 1024*256
    float* winvT = xc   + (size_t)M_ * 256;    // 65536
    float* bresT = winvT + (size_t)NN_ * D_;   // 65536
    float* hwinv = bresT + (size_t)NN_ * D_;   // 1024*256
    float* hcbuf = hwinv + (size_t)M_ * D_;    // 1024*256
    // ushort region
    unsigned short* us = (unsigned short*)(hcbuf + (size_t)M_ * D_);
    unsigned short* hri_h = us;                       us += (size_t)M_ * 512;
    unsigned short* hri_l = us;                       us += (size_t)M_ * 512;
    unsigned short* G_h   = us;                       us += (size_t)M_ * 768;
    unsigned short* G_l   = us;                       us += (size_t)M_ * 768;
    unsigned short* BB_h  = us;                       us += (size_t)256 * 768;
    unsigned short* BB_l  = us;                       us += (size_t)256 * 768;
    unsigned short* Wc_h  = us;                       us += (size_t)256 * 512;
    unsigned short* Wc_l  = us;                       us += (size_t)256 * 512;
    unsigned short* fus16 = us;                       us += (size_t)M_ * 256;
    unsigned short* Wo16  = us;

    // 1. h prep (critical path)
    k_prep_h<<<dim3(M_), dim3(256), 0, stream>>>(ids, emb, hwinv, hcbuf);
    // 2. hscan (8 blocks) + all weight preps on the otherwise-idle CUs
    k_hscan_plus<<<dim3(4584), dim3(256), 0, stream>>>(
        hwinv, hcbuf, Wres, Bres, Wout, Wc, Wr, Wi, Wor, Woi,
        hri_h, hri_l, xbuf, winvT, bresT,
        Wo16, Wc_h, Wc_l, BB_h, BB_l);
    // 3. Q/K phase vectors + gemm1 (xc), mutually independent -> one launch
    k_qk_gemm1<<<dim3(16 + 2048), dim3(256), 0, stream>>>(
        xbuf, wq, bq, wk, bk, qbuf, kbuf,
        hri_h, hri_l, Wc_h, Wc_l, bc, xc);
    // 4. attention + resonant, concurrent (disjoint G columns)
    k_attn_res<<<dim3(M_ + M_ / 2), dim3(256), 0, stream>>>(
        qbuf, kbuf, xbuf, xc, winvT, bresT, G_h, G_l);
    // 5. fused = G @ BB^T  (M=1024, N=256, K=768) via MFMA, fp16 epilogue
    gemm_fused<<<dim3(2, 8), dim3(256), 0, stream>>>(
        G_h, G_l, BB_h, BB_l, fus16);
    // 6. logits = fused @ Wout^T via single-term fp16 MFMA
    gemm_logits4<<<dim3(2048), dim3(256), 0, stream>>>(fus16, Wo16, out);
}

// Round 13
// 138.808 us; speedup vs baseline: 1.6398x; 1.1609x over previous
//
#include <hip/hip_runtime.h>
#include <math.h>

// ---------------- constants ----------------
#define PHI_F      ((float)1.6180339887498948482045868343656381177)
#define B_  8
#define S_  128
#define D_  256
#define H_  8
#define DH_ 32
#define NN_ 256
#define V_  32000
#define M_  (B_ * S_)   // 1024 rows, m = t*8 + b

typedef __attribute__((ext_vector_type(4))) float f32x4;
typedef __attribute__((ext_vector_type(8))) short bf16x8;
typedef _Float16 f16x8 __attribute__((ext_vector_type(8)));

__device__ __forceinline__ unsigned short f2bf_rne(float x) {
    unsigned u = __float_as_uint(x);
    unsigned r = (u + 0x7FFFu + ((u >> 16) & 1u)) >> 16;
    return (unsigned short)r;
}

__device__ __forceinline__ void split_hl(float x, unsigned short& h, unsigned short& l) {
    h = f2bf_rne(x);
    float hf = __uint_as_float(((unsigned)h) << 16);
    l = f2bf_rne(__fsub_rn(x, hf));
}

__device__ __forceinline__ unsigned short f2h_bits(float x) {
    _Float16 h = (_Float16)x;     // v_cvt_f16_f32, RNE
    unsigned short u;
    __builtin_memcpy(&u, &h, 2);
    return u;
}

// ---------------- K1: hscan (8 blocks, prep inlined) + weight preps ---------
// [0,8): h-recurrence with inline emb prep; [8,264): res prep;
// [264,392): Wc split; [392,584): BB build+split; [584,4584): Wout -> fp16.
__global__ __launch_bounds__(256) void k_hscan_plus(
    const int* __restrict__ ids, const float* __restrict__ emb,
    const float* __restrict__ Wres, const float* __restrict__ Bres,
    const float* __restrict__ Wout, const float* __restrict__ Wc,
    const float* __restrict__ Wr, const float* __restrict__ Wi,
    const float* __restrict__ Wor, const float* __restrict__ Woi,
    unsigned short* __restrict__ hri_h, unsigned short* __restrict__ hri_l,
    float* __restrict__ xbuf,
    float* __restrict__ winvT, float* __restrict__ bresT,
    unsigned short* __restrict__ Wo16,
    unsigned short* __restrict__ Wc_h, unsigned short* __restrict__ Wc_l,
    unsigned short* __restrict__ BB_h, unsigned short* __restrict__ BB_l)
{
    __shared__ int s_ids[S_];
    const int blk = blockIdx.x;
    const int tid = threadIdx.x;
    if (blk < 8) {
        // scan runs concurrent with the 4000-block Wout convert -> its extra
        // per-step prep work (emb loads + exact div, x-independent) is free.
        int b = blk, d = tid;
        if (tid < S_) s_ids[tid] = ids[b * S_ + tid];
        __syncthreads();
        float x = 0.f;
        #pragma unroll 4
        for (int t = 0; t < S_; ++t) {
            int m = (t << 3) | b;
            int id = s_ids[t];
            float w  = emb[(size_t)id * (2 * D_) + d];
            float bt = emb[(size_t)id * (2 * D_) + D_ + d];
            float wi = 1.0f / (1.0f + fabsf(w));
            float c  = 2.0f * (bt + (float)t * PHI_F);
            float u  = fmaf(x, wi, c);
            float s, co;
            __sincosf(u, &s, &co);
            x = co + s;
            ushort hh, hl, sh, sl;
            split_hl(co, hh, hl);
            split_hl(s,  sh, sl);
            hri_h[(size_t)m * 512 + d]       = hh;
            hri_l[(size_t)m * 512 + d]       = hl;
            hri_h[(size_t)m * 512 + 256 + d] = sh;
            hri_l[(size_t)m * 512 + 256 + d] = sl;
            xbuf[(size_t)m * D_ + d]         = x;
        }
    } else if (blk < 264) {
        int i = (blk - 8) * 256 + tid;        // i = n*256+d
        int n = i >> 8, d = i & 255;
        winvT[d * NN_ + n] = 1.0f / (1.0f + fabsf(Wres[i]));
        bresT[d * NN_ + n] = Bres[i];
    } else if (blk < 392) {
        int i = ((blk - 264) * 256 + tid) * 4;    // < 256*512
        float4 v = *(const float4*)&Wc[i];
        float xs[4] = {v.x, v.y, v.z, v.w};
        ushort hs[4], ls[4];
        #pragma unroll
        for (int j = 0; j < 4; ++j) split_hl(xs[j], hs[j], ls[j]);
        *(ushort4*)&Wc_h[i] = make_ushort4(hs[0], hs[1], hs[2], hs[3]);
        *(ushort4*)&Wc_l[i] = make_ushort4(ls[0], ls[1], ls[2], ls[3]);
    } else if (blk < 584) {
        int i = ((blk - 392) * 256 + tid) * 4;    // < 256*768, BB[n][k]
        int n = i / 768, k = i % 768;
        float4 v;
        if (k < 256) {
            float4 a = *(const float4*)&Wr[n * 256 + k];
            float4 b = *(const float4*)&Wi[n * 256 + k];
            v.x = a.x + b.x; v.y = a.y + b.y; v.z = a.z + b.z; v.w = a.w + b.w;
        } else if (k < 512) {
            v = *(const float4*)&Wor[n * 256 + (k - 256)];
        } else {
            v = *(const float4*)&Woi[n * 256 + (k - 512)];
        }
        float xs[4] = {v.x, v.y, v.z, v.w};
        ushort hs[4], ls[4];
        #pragma unroll
        for (int j = 0; j < 4; ++j) split_hl(xs[j], hs[j], ls[j]);
        *(ushort4*)&BB_h[i] = make_ushort4(hs[0], hs[1], hs[2], hs[3]);
        *(ushort4*)&BB_l[i] = make_ushort4(ls[0], ls[1], ls[2], ls[3]);
    } else {
        int i = ((blk - 584) * 256 + tid) * 8;    // < V_*256, 8/thread
        float4 v0 = *(const float4*)&Wout[i];
        float4 v1 = *(const float4*)&Wout[i + 4];
        ushort4 o0 = make_ushort4(f2h_bits(v0.x), f2h_bits(v0.y), f2h_bits(v0.z), f2h_bits(v0.w));
        ushort4 o1 = make_ushort4(f2h_bits(v1.x), f2h_bits(v1.y), f2h_bits(v1.z), f2h_bits(v1.w));
        *(ushort4*)&Wo16[i]     = o0;
        *(ushort4*)&Wo16[i + 4] = o1;
    }
}

// ---------------- K2: merged gemm1 (blocks [0,64), 64x64 tiles) + qk --------
// gemm1: xc = [h_r|h_i] @ Wc^T + bc, K=512. 64 blocks -> 4x the CU coverage
// of the old 16-block 128x128 tiling (latency-bound regime).
__global__ __launch_bounds__(256) void k_qk_gemm1(
    const float* __restrict__ xbuf,
    const float* __restrict__ wq, const float* __restrict__ bq,
    const float* __restrict__ wk, const float* __restrict__ bk,
    float* __restrict__ qbuf, float* __restrict__ kbuf,
    const unsigned short* __restrict__ Ah, const unsigned short* __restrict__ Al,
    const unsigned short* __restrict__ Bh, const unsigned short* __restrict__ Bl,
    const float* __restrict__ bias, float* __restrict__ xc)
{
    __shared__ unsigned short sAh[64 * 64], sAl[64 * 64];
    __shared__ unsigned short sBh[64 * 64], sBl[64 * 64];
    const int tid = threadIdx.x;

    if (blockIdx.x >= 64) {
        // ---------------- qk ----------------
        int i = (blockIdx.x - 64) * 256 + tid;        // 0 .. 2*half-1
        const int half = S_ * B_ * H_ * DH_;          // 262144
        bool isq = (i < half);
        int r = isq ? i : i - half;
        int j = r & 31;
        int h = (r >> 5) & 7;
        int b = (r >> 8) & 7;
        int t = r >> 11;
        int m = (t << 3) | b;
        float xv = xbuf[(size_t)m * D_ + h * DH_ + j];
        const float* W  = isq ? wq : wk;
        const float* Bv = isq ? bq : bk;
        float inv = 1.0f / (1.0f + fabsf(W[h * DH_ + j]));
        float th = fmaf(xv, inv, Bv[h * DH_ + j]);
        if (isq) th += (float)t * PHI_F;
        float s, c;
        __sincosf(th, &s, &c);
        float* out = isq ? qbuf : kbuf;
        out[(size_t)m * 512 + h * 64 + j]      = c;
        out[(size_t)m * 512 + h * 64 + 32 + j] = s;
        return;
    }

    // ---------------- gemm1, 64x64 tile ----------------
    const int n0 = (blockIdx.x & 3) * 64;     // N=256 -> 4 n-tiles
    const int m0 = (blockIdx.x >> 2) * 64;    // M=1024 -> 16 m-tiles
    const int lane = tid & 63;
    const int wv   = tid >> 6;
    const int wr   = wv >> 1, wc = wv & 1;
    f32x4 acc[2][2] = {};

    for (int k0 = 0; k0 < 512; k0 += 64) {
        #pragma unroll
        for (int q = 0; q < 2; ++q) {
            int idx  = q * 256 + tid;          // 0..511
            int row  = idx >> 3;               // 0..63
            int slot = (idx & 7) ^ (row & 7);
            int ldsbase = (q * 256 + wv * 64) * 8;
            size_t ga = (size_t)(m0 + row) * 512 + k0 + slot * 8;
            size_t gb = (size_t)(n0 + row) * 512 + k0 + slot * 8;
            __builtin_amdgcn_global_load_lds(
                (const __attribute__((address_space(1))) void*)(Ah + ga),
                (__attribute__((address_space(3))) void*)(sAh + ldsbase), 16, 0, 0);
            __builtin_amdgcn_global_load_lds(
                (const __attribute__((address_space(1))) void*)(Al + ga),
                (__attribute__((address_space(3))) void*)(sAl + ldsbase), 16, 0, 0);
            __builtin_amdgcn_global_load_lds(
                (const __attribute__((address_space(1))) void*)(Bh + gb),
                (__attribute__((address_space(3))) void*)(sBh + ldsbase), 16, 0, 0);
            __builtin_amdgcn_global_load_lds(
                (const __attribute__((address_space(1))) void*)(Bl + gb),
                (__attribute__((address_space(3))) void*)(sBl + ldsbase), 16, 0, 0);
        }
        __syncthreads();

        #pragma unroll
        for (int ks = 0; ks < 2; ++ks) {
            const int kg = ks * 4 + (lane >> 4);
            bf16x8 afh[2], afl[2], bfh[2], bfl[2];
            #pragma unroll
            for (int mi = 0; mi < 2; ++mi) {
                int row  = wr * 32 + mi * 16 + (lane & 15);
                int slot = kg ^ (row & 7);
                afh[mi] = *(const bf16x8*)&sAh[row * 64 + slot * 8];
                afl[mi] = *(const bf16x8*)&sAl[row * 64 + slot * 8];
            }
            #pragma unroll
            for (int nj = 0; nj < 2; ++nj) {
                int row  = wc * 32 + nj * 16 + (lane & 15);
                int slot = kg ^ (row & 7);
                bfh[nj] = *(const bf16x8*)&sBh[row * 64 + slot * 8];
                bfl[nj] = *(const bf16x8*)&sBl[row * 64 + slot * 8];
            }
            #pragma unroll
            for (int mi = 0; mi < 2; ++mi)
                #pragma unroll
                for (int nj = 0; nj < 2; ++nj) {
                    acc[mi][nj] = __builtin_amdgcn_mfma_f32_16x16x32_bf16(afh[mi], bfh[nj], acc[mi][nj], 0, 0, 0);
                    acc[mi][nj] = __builtin_amdgcn_mfma_f32_16x16x32_bf16(afh[mi], bfl[nj], acc[mi][nj], 0, 0, 0);
                    acc[mi][nj] = __builtin_amdgcn_mfma_f32_16x16x32_bf16(afl[mi], bfh[nj], acc[mi][nj], 0, 0, 0);
                }
        }
        __syncthreads();
    }

    #pragma unroll
    for (int mi = 0; mi < 2; ++mi)
        #pragma unroll
        for (int nj = 0; nj < 2; ++nj)
            #pragma unroll
            for (int r = 0; r < 4; ++r) {
                int m = m0 + wr * 32 + mi * 16 + (lane >> 4) * 4 + r;
                int n = n0 + wc * 32 + nj * 16 + (lane & 15);
                xc[(size_t)m * 256 + n] = acc[mi][nj][r] + bias[n];
            }
}

// ---------------- K3: merged attention (blocks [0,1024)) + resonant ---------
__global__ __launch_bounds__(256) void k_attn_res(
    const float* __restrict__ qbuf, const float* __restrict__ kbuf,
    const float* __restrict__ xbuf, const float* __restrict__ xc,
    const float* __restrict__ winvT, const float* __restrict__ bresT,
    unsigned short* __restrict__ G_h, unsigned short* __restrict__ G_l)
{
    __shared__ float qs[512];
    __shared__ float sc[8][128];
    __shared__ float invdn[8];
    __shared__ float wsum[128];
    const int tid = threadIdx.x;

    if (blockIdx.x < M_) {
        int m = blockIdx.x;
        int t = m >> 3, b = m & 7;
        if (t == 0) {
            G_h[(size_t)m * 768 + tid] = 0;
            G_l[(size_t)m * 768 + tid] = 0;
            return;
        }
        qs[tid]       = qbuf[(size_t)m * 512 + tid];
        qs[tid + 256] = qbuf[(size_t)m * 512 + 256 + tid];
        __syncthreads();
        int h = tid & 7;
        for (int s = tid >> 3; s < t; s += 32) {
            const float* kk = kbuf + (size_t)((s << 3) | b) * 512 + h * 64;
            const float* qq = qs + h * 64;
            float dot = 0.f;
            #pragma unroll
            for (int e = 0; e < 64; ++e) dot += qq[e] * kk[e];
            sc[h][s] = dot * 0.125f;
        }
        __syncthreads();
        int hh = tid >> 5, j = tid & 31;
        float mx = -1e30f;
        for (int s = j; s < t; s += 32) mx = fmaxf(mx, sc[hh][s]);
        #pragma unroll
        for (int o = 16; o; o >>= 1) mx = fmaxf(mx, __shfl_xor(mx, o, 32));
        float dn = 0.f;
        for (int s = j; s < t; s += 32) {
            float e2 = expf(sc[hh][s] - mx);
            sc[hh][s] = e2;
            dn += e2;
        }
        #pragma unroll
        for (int o = 16; o; o >>= 1) dn += __shfl_xor(dn, o, 32);
        if (j == 0) invdn[hh] = 1.0f / dn;
        __syncthreads();
        if (tid < t) {
            float wv = 0.f;
            #pragma unroll
            for (int h2 = 0; h2 < 8; ++h2) wv += sc[h2][tid] * invdn[h2];
            wsum[tid] = wv;
        }
        __syncthreads();
        float a0 = 0.f, a1 = 0.f, a2 = 0.f, a3 = 0.f;
        int s = 0;
        for (; s + 4 <= t; s += 4) {
            a0 += wsum[s + 0] * xbuf[(size_t)(((s + 0) << 3) | b) * D_ + tid];
            a1 += wsum[s + 1] * xbuf[(size_t)(((s + 1) << 3) | b) * D_ + tid];
            a2 += wsum[s + 2] * xbuf[(size_t)(((s + 2) << 3) | b) * D_ + tid];
            a3 += wsum[s + 3] * xbuf[(size_t)(((s + 3) << 3) | b) * D_ + tid];
        }
        for (; s < t; ++s) a0 += wsum[s] * xbuf[(size_t)((s << 3) | b) * D_ + tid];
        float v = (a0 + a1) + (a2 + a3);
        ushort hu, lu;
        split_hl(v, hu, lu);
        G_h[(size_t)m * 768 + tid] = hu;
        G_l[(size_t)m * 768 + tid] = lu;
    } else {
        const int m0 = (blockIdx.x - M_) * 2;
        float* s_xc0 = qs;
        float* s_xc1 = qs + 256;
        s_xc0[tid] = xc[(size_t)m0 * D_ + tid];
        s_xc1[tid] = xc[(size_t)(m0 + 1) * D_ + tid];
        __syncthreads();
        const int n = tid;
        const float tp = __fmul_rn((float)(m0 >> 3), PHI_F);
        float cs0 = 0.f, ss0 = 0.f, cs1 = 0.f, ss1 = 0.f;
        #pragma unroll 4
        for (int d = 0; d < D_; ++d) {
            float wi = winvT[d * NN_ + n];
            float bt = bresT[d * NN_ + n] + tp;
            float th0 = fmaf(s_xc0[d], wi, bt);
            float th1 = fmaf(s_xc1[d], wi, bt);
            cs0 += __cosf(th0); ss0 += __sinf(th0);
            cs1 += __cosf(th1); ss1 += __sinf(th1);
        }
        ushort h0, l0, h1, l1, h2, l2, h3, l3;
        split_hl(cs0, h0, l0); split_hl(ss0, h1, l1);
        split_hl(cs1, h2, l2); split_hl(ss1, h3, l3);
        G_h[(size_t)m0 * 768 + 256 + n] = h0; G_l[(size_t)m0 * 768 + 256 + n] = l0;
        G_h[(size_t)m0 * 768 + 512 + n] = h1; G_l[(size_t)m0 * 768 + 512 + n] = l1;
        G_h[(size_t)(m0 + 1) * 768 + 256 + n] = h2; G_l[(size_t)(m0 + 1) * 768 + 256 + n] = l2;
        G_h[(size_t)(m0 + 1) * 768 + 512 + n] = h3; G_l[(size_t)(m0 + 1) * 768 + 512 + n] = l3;
    }
}

// ---------------- gemm2: 64x64 tiles, K=768, fp16 epilogue ------------------
__global__ __launch_bounds__(256) void gemm_fused(
    const unsigned short* __restrict__ Ah, const unsigned short* __restrict__ Al,
    const unsigned short* __restrict__ Bh, const unsigned short* __restrict__ Bl,
    unsigned short* __restrict__ O16)
{
    __shared__ unsigned short sAh[64 * 64], sAl[64 * 64];
    __shared__ unsigned short sBh[64 * 64], sBl[64 * 64];
    const int n0 = blockIdx.x * 64;           // N=256 -> 4
    const int m0 = blockIdx.y * 64;           // M=1024 -> 16
    const int tid  = threadIdx.x;
    const int lane = tid & 63;
    const int wv   = tid >> 6;
    const int wr   = wv >> 1, wc = wv & 1;
    f32x4 acc[2][2] = {};

    for (int k0 = 0; k0 < 768; k0 += 64) {
        #pragma unroll
        for (int q = 0; q < 2; ++q) {
            int idx  = q * 256 + tid;
            int row  = idx >> 3;
            int slot = (idx & 7) ^ (row & 7);
            int ldsbase = (q * 256 + wv * 64) * 8;
            size_t ga = (size_t)(m0 + row) * 768 + k0 + slot * 8;
            size_t gb = (size_t)(n0 + row) * 768 + k0 + slot * 8;
            __builtin_amdgcn_global_load_lds(
                (const __attribute__((address_space(1))) void*)(Ah + ga),
                (__attribute__((address_space(3))) void*)(sAh + ldsbase), 16, 0, 0);
            __builtin_amdgcn_global_load_lds(
                (const __attribute__((address_space(1))) void*)(Al + ga),
                (__attribute__((address_space(3))) void*)(sAl + ldsbase), 16, 0, 0);
            __builtin_amdgcn_global_load_lds(
                (const __attribute__((address_space(1))) void*)(Bh + gb),
                (__attribute__((address_space(3))) void*)(sBh + ldsbase), 16, 0, 0);
            __builtin_amdgcn_global_load_lds(
                (const __attribute__((address_space(1))) void*)(Bl + gb),
                (__attribute__((address_space(3))) void*)(sBl + ldsbase), 16, 0, 0);
        }
        __syncthreads();

        #pragma unroll
        for (int ks = 0; ks < 2; ++ks) {
            const int kg = ks * 4 + (lane >> 4);
            bf16x8 afh[2], afl[2], bfh[2], bfl[2];
            #pragma unroll
            for (int mi = 0; mi < 2; ++mi) {
                int row  = wr * 32 + mi * 16 + (lane & 15);
                int slot = kg ^ (row & 7);
                afh[mi] = *(const bf16x8*)&sAh[row * 64 + slot * 8];
                afl[mi] = *(const bf16x8*)&sAl[row * 64 + slot * 8];
            }
            #pragma unroll
            for (int nj = 0; nj < 2; ++nj) {
                int row  = wc * 32 + nj * 16 + (lane & 15);
                int slot = kg ^ (row & 7);
                bfh[nj] = *(const bf16x8*)&sBh[row * 64 + slot * 8];
                bfl[nj] = *(const bf16x8*)&sBl[row * 64 + slot * 8];
            }
            #pragma unroll
            for (int mi = 0; mi < 2; ++mi)
                #pragma unroll
                for (int nj = 0; nj < 2; ++nj) {
                    acc[mi][nj] = __builtin_amdgcn_mfma_f32_16x16x32_bf16(afh[mi], bfh[nj], acc[mi][nj], 0, 0, 0);
                    acc[mi][nj] = __builtin_amdgcn_mfma_f32_16x16x32_bf16(afh[mi], bfl[nj], acc[mi][nj], 0, 0, 0);
                    acc[mi][nj] = __builtin_amdgcn_mfma_f32_16x16x32_bf16(afl[mi], bfh[nj], acc[mi][nj], 0, 0, 0);
                }
        }
        __syncthreads();
    }

    #pragma unroll
    for (int mi = 0; mi < 2; ++mi)
        #pragma unroll
        for (int nj = 0; nj < 2; ++nj)
            #pragma unroll
            for (int r = 0; r < 4; ++r) {
                int m = m0 + wr * 32 + mi * 16 + (lane >> 4) * 4 + r;
                int n = n0 + wc * 32 + nj * 16 + (lane & 15);
                O16[(size_t)m * 256 + n] = f2h_bits(acc[mi][nj][r]);
            }
}

// ---------------- K7 v4: logits GEMM, fp16 single-term, XCD-panel-grouped ---
__global__ __launch_bounds__(256) void gemm_logits4(
    const unsigned short* __restrict__ A16, const unsigned short* __restrict__ B16,
    float* __restrict__ out)
{
    const int blk = blockIdx.x;
    const int r = blk & 7, mt = (blk >> 3) & 7, j = blk >> 6;
    const int p = j * 8 + r;
    if (p >= V_ / 128) return;
    const int n0 = p * 128;
    const int m0 = mt * 128;

    __shared__ unsigned short sA[128 * 64], sB[128 * 64];
    const int tid  = threadIdx.x;
    const int lane = tid & 63;
    const int wv   = tid >> 6;
    const int wr   = wv >> 1, wc = wv & 1;
    f32x4 acc[4][4] = {};

    for (int k0 = 0; k0 < 256; k0 += 64) {
        #pragma unroll
        for (int q = 0; q < 4; ++q) {
            int idx  = q * 256 + tid;
            int row  = idx >> 3;
            int slot = (idx & 7) ^ (row & 7);
            int ldsbase = (q * 256 + wv * 64) * 8;
            size_t ga = (size_t)(m0 + row) * 256 + k0 + slot * 8;
            size_t gb = (size_t)(n0 + row) * 256 + k0 + slot * 8;
            __builtin_amdgcn_global_load_lds(
                (const __attribute__((address_space(1))) void*)(A16 + ga),
                (__attribute__((address_space(3))) void*)(sA + ldsbase), 16, 0, 0);
            __builtin_amdgcn_global_load_lds(
                (const __attribute__((address_space(1))) void*)(B16 + gb),
                (__attribute__((address_space(3))) void*)(sB + ldsbase), 16, 0, 0);
        }
        __syncthreads();

        #pragma unroll
        for (int ks = 0; ks < 2; ++ks) {
            const int kg = ks * 4 + (lane >> 4);
            f16x8 af[4], bf[4];
            #pragma unroll
            for (int mi = 0; mi < 4; ++mi) {
                int row  = wr * 64 + mi * 16 + (lane & 15);
                int slot = kg ^ (row & 7);
                af[mi] = *(const f16x8*)&sA[row * 64 + slot * 8];
            }
            #pragma unroll
            for (int nj = 0; nj < 4; ++nj) {
                int row  = wc * 64 + nj * 16 + (lane & 15);
                int slot = kg ^ (row & 7);
                bf[nj] = *(const f16x8*)&sB[row * 64 + slot * 8];
            }
            #pragma unroll
            for (int mi = 0; mi < 4; ++mi)
                #pragma unroll
                for (int nj = 0; nj < 4; ++nj)
                    acc[mi][nj] = __builtin_amdgcn_mfma_f32_16x16x32_f16(af[mi], bf[nj], acc[mi][nj], 0, 0, 0);
        }
        __syncthreads();
    }

    #pragma unroll
    for (int mi = 0; mi < 4; ++mi)
        #pragma unroll
        for (int nj = 0; nj < 4; ++nj)
            #pragma unroll
            for (int rr = 0; rr < 4; ++rr) {
                int m = m0 + wr * 64 + mi * 16 + (lane >> 4) * 4 + rr;
                int n = n0 + wc * 64 + nj * 16 + (lane & 15);
                int orow = (m & 7) * S_ + (m >> 3);
                out[(size_t)orow * V_ + n] = acc[mi][nj][rr];
            }
}

// ---------------- launcher ----------------
extern "C" void kernel_launch(void* const* d_in, const int* in_sizes, int n_in,
                              void* d_out, int out_size, void* d_ws, size_t ws_size,
                              hipStream_t stream)
{
    const int*   ids  = (const int*)d_in[0];
    const float* emb  = (const float*)d_in[1];
    const float* wq   = (const float*)d_in[2];
    const float* bq   = (const float*)d_in[3];
    const float* wk   = (const float*)d_in[4];
    const float* bk   = (const float*)d_in[5];
    const float* Wr   = (const float*)d_in[6];
    const float* Wi   = (const float*)d_in[7];
    const float* Wc   = (const float*)d_in[8];
    const float* bc   = (const float*)d_in[9];
    const float* Wres = (const float*)d_in[10];
    const float* Bres = (const float*)d_in[11];
    const float* Wor  = (const float*)d_in[12];
    const float* Woi  = (const float*)d_in[13];
    const float* Wout = (const float*)d_in[14];
    float* out = (float*)d_out;
    float* ws  = (float*)d_ws;

    // f32 region
    float* xbuf  = ws;                         // 1024*256
    float* qbuf  = xbuf + (size_t)M_ * 256;    // 1024*512
    float* kbuf  = qbuf + (size_t)M_ * 512;    // 1024*512
    float* xc    = kbuf + (size_t)M_ * 512;    // 1024*256
    float* winvT = xc   + (size_t)M_ * 256;    // 65536
    float* bresT = winvT + (size_t)NN_ * D_;   // 65536
    // ushort region
    unsigned short* us = (unsigned short*)(bresT + (size_t)NN_ * D_);
    unsigned short* hri_h = us;                       us += (size_t)M_ * 512;
    unsigned short* hri_l = us;                       us += (size_t)M_ * 512;
    unsigned short* G_h   = us;                       us += (size_t)M_ * 768;
    unsigned short* G_l   = us;                       us += (size_t)M_ * 768;
    unsigned short* BB_h  = us;                       us += (size_t)256 * 768;
    unsigned short* BB_l  = us;                       us += (size_t)256 * 768;
    unsigned short* Wc_h  = us;                       us += (size_t)256 * 512;
    unsigned short* Wc_l  = us;                       us += (size_t)256 * 512;
    unsigned short* fus16 = us;                       us += (size_t)M_ * 256;
    unsigned short* Wo16  = us;

    // 1. hscan (8 blocks, prep inlined) + all weight preps on idle CUs
    k_hscan_plus<<<dim3(4584), dim3(256), 0, stream>>>(
        ids, emb, Wres, Bres, Wout, Wc, Wr, Wi, Wor, Woi,
        hri_h, hri_l, xbuf, winvT, bresT,
        Wo16, Wc_h, Wc_l, BB_h, BB_l);
    // 2. Q/K phase vectors + gemm1 (xc), mutually independent -> one launch
    k_qk_gemm1<<<dim3(64 + 2048), dim3(256), 0, stream>>>(
        xbuf, wq, bq, wk, bk, qbuf, kbuf,
        hri_h, hri_l, Wc_h, Wc_l, bc, xc);
    // 3. attention + resonant, concurrent (disjoint G columns)
    k_attn_res<<<dim3(M_ + M_ / 2), dim3(256), 0, stream>>>(
        qbuf, kbuf, xbuf, xc, winvT, bresT, G_h, G_l);
    // 4. fused = G @ BB^T  (M=1024, N=256, K=768), 64x64 tiles, fp16 epilogue
    gemm_fused<<<dim3(4, 16), dim3(256), 0, stream>>>(
        G_h, G_l, BB_h, BB_l, fus16);
    // 5. logits = fused @ Wout^T via single-term fp16 MFMA
    gemm_logits4<<<dim3(2048), dim3(256), 0, stream>>>(fus16, Wo16, out);
}